// Round 6
// baseline (525.112 us; speedup 1.0000x reference)
//
#include <hip/hip_runtime.h>
#include <hip/hip_bf16.h>
#include <hip/hip_fp16.h>

#define DEV_INLINE __device__ __forceinline__

static DEV_INLINE float4 ld4(const float* p){ return *reinterpret_cast<const float4*>(p); }

#define GNUM 64
#define CHUNK 4096
#define MAXNB 1024   // bucket = dst>>7; N <= 65536 (u16 packing)

// ======================= bucketed edge build =======================
__global__ __launch_bounds__(256) void k_hist(const int* __restrict__ dst, int E, int NB,
                                              int* __restrict__ bcnt){
    __shared__ int cnt[MAXNB];
    int t = threadIdx.x; int base0 = blockIdx.x*CHUNK;
    for (int i=t;i<NB;i+=256) cnt[i]=0;
    __syncthreads();
    int tot = E - base0; if (tot > CHUNK) tot = CHUNK;
    #pragma unroll
    for (int k=0;k<16;k++){
        int o = t + k*256;
        if (o < tot) atomicAdd(&cnt[dst[base0+o]>>7], 1);
    }
    __syncthreads();
    for (int i=t;i<NB;i+=256) if (cnt[i]) atomicAdd(&bcnt[i], cnt[i]);
}

// one-block exclusive scan (M<=1024) + fused graph-boundary binary search
__global__ void k_scan1b(const int* __restrict__ in, int* __restrict__ out, int M, int total,
                         const int* __restrict__ batch, int N, int* __restrict__ gstart){
    __shared__ int ws[4];
    int t = threadIdx.x;
    int i0 = t*4;
    int c0=(i0+0<M)?in[i0+0]:0, c1=(i0+1<M)?in[i0+1]:0;
    int c2=(i0+2<M)?in[i0+2]:0, c3=(i0+3<M)?in[i0+3]:0;
    int tsum=c0+c1+c2+c3;
    int lane=t&63, w=t>>6;
    int x=tsum;
    for (int off=1;off<64;off<<=1){ int yv=__shfl_up(x,off); if (lane>=off) x+=yv; }
    if (lane==63) ws[w]=x;
    __syncthreads();
    if (t==0){ int a=0; for (int i=0;i<4;i++){ int tmp=ws[i]; ws[i]=a; a+=tmp; } }
    __syncthreads();
    int ex = x - tsum + ws[w];
    if (i0+0<M) out[i0+0]=ex; ex+=c0;
    if (i0+1<M) out[i0+1]=ex; ex+=c1;
    if (i0+2<M) out[i0+2]=ex; ex+=c2;
    if (i0+3<M) out[i0+3]=ex;
    if (t==0 && total>=0) out[M]=total;
    // fused: graph boundaries (batch sorted)
    if (t <= GNUM){
        int lo = 0, hi = N;
        while (lo < hi){ int mid = (lo+hi)>>1; if (batch[mid] < t) lo = mid+1; else hi = mid; }
        gstart[t] = lo;
    }
}

__global__ __launch_bounds__(256) void k_scatter(const int* __restrict__ src, const int* __restrict__ dst,
                                                 int E, int NB, const int* __restrict__ bbase,
                                                 int* __restrict__ bfill, unsigned* __restrict__ ebuf){
    __shared__ int cnt[MAXNB];
    __shared__ int pfx[MAXNB];
    __shared__ int gbase[MAXNB];
    __shared__ unsigned stage[CHUNK];
    __shared__ int ws[4];
    int t = threadIdx.x; int base0 = blockIdx.x*CHUNK;
    int tot = E - base0; if (tot > CHUNK) tot = CHUNK;
    for (int i=t;i<NB;i+=256) cnt[i]=0;
    __syncthreads();
    unsigned v[16]; int rk[16];
    #pragma unroll
    for (int k=0;k<16;k++){
        int o = t + k*256;
        if (o < tot){
            int e = base0 + o;
            int s = src[e], d = dst[e];
            v[k] = (unsigned)s | ((unsigned)d<<16);
            rk[k] = atomicAdd(&cnt[d>>7], 1);
        } else { v[k]=0u; rk[k]=-1; }
    }
    __syncthreads();
    int i0 = t*4;
    int c0=(i0+0<NB)?cnt[i0+0]:0, c1=(i0+1<NB)?cnt[i0+1]:0;
    int c2=(i0+2<NB)?cnt[i0+2]:0, c3=(i0+3<NB)?cnt[i0+3]:0;
    int tsum=c0+c1+c2+c3;
    int lane=t&63, w=t>>6;
    int x=tsum;
    for (int off=1;off<64;off<<=1){ int yv=__shfl_up(x,off); if (lane>=off) x+=yv; }
    if (lane==63) ws[w]=x;
    __syncthreads();
    if (t==0){ int a=0; for (int i=0;i<4;i++){ int tmp=ws[i]; ws[i]=a; a+=tmp; } }
    __syncthreads();
    int ex = x - tsum + ws[w];
    if (i0+0<NB) pfx[i0+0]=ex; ex+=c0;
    if (i0+1<NB) pfx[i0+1]=ex; ex+=c1;
    if (i0+2<NB) pfx[i0+2]=ex; ex+=c2;
    if (i0+3<NB) pfx[i0+3]=ex;
    __syncthreads();
    for (int i=t;i<NB;i+=256){
        int c = cnt[i];
        gbase[i] = c ? (bbase[i] + atomicAdd(&bfill[i], c)) : 0;
    }
    __syncthreads();
    #pragma unroll
    for (int k=0;k<16;k++) if (rk[k]>=0){ int b = (int)(v[k]>>23); stage[pfx[b]+rk[k]] = v[k]; }
    __syncthreads();
    for (int j=t;j<tot;j+=256){
        unsigned u = stage[j];
        int b = (int)(u>>23);
        ebuf[gbase[b] + (j - pfx[b])] = u;
    }
}

// fused: per-bucket degree count -> in-LDS prefix -> rs + dinv -> CSR fill
__global__ __launch_bounds__(256) void k_bucket_finish(const unsigned* __restrict__ ebuf,
                                                       const int* __restrict__ bbase,
                                                       int* __restrict__ rs, int* __restrict__ csr,
                                                       float* __restrict__ dinv, int N, int E){
    __shared__ int c2[128];
    __shared__ int rsl[128];
    __shared__ int ws[4];
    int b = blockIdx.x, t = threadIdx.x;
    if (t < 128) c2[t] = 0;
    __syncthreads();
    int s0 = bbase[b], s1 = bbase[b+1];
    for (int j = s0+t; j < s1; j += 256)
        atomicAdd(&c2[(ebuf[j]>>16)&127], 1);
    __syncthreads();
    // exclusive scan of c2[0..127] (waves 0,1 carry data)
    int v = (t < 128) ? c2[t] : 0;
    int lane = t & 63, w = t >> 6;
    int x = v;
    for (int off=1; off<64; off<<=1){
        int yv = __shfl_up(x, off);
        if (lane >= off) x += yv;
    }
    if (lane == 63) ws[w] = x;
    __syncthreads();
    if (t < 128){
        int ex = x - v + ((w == 1) ? ws[0] : 0);
        rsl[t] = s0 + ex;
        int node = (b<<7) + t;
        if (node < N){
            rs[node] = s0 + ex;
            dinv[node] = rsqrtf((float)(v + 1));
        }
    }
    if (b == (int)gridDim.x - 1 && t == 0) rs[N] = E;
    __syncthreads();
    if (t < 128) c2[t] = 0;
    __syncthreads();
    for (int j = s0+t; j < s1; j += 256){
        unsigned u = ebuf[j];
        int ld = (u>>16)&127;
        int p = atomicAdd(&c2[ld], 1);
        csr[rsl[ld]+p] = (int)(u & 0xffffu);
    }
}

// ---------------- GEMM1: y = (X @ W1) * dinv[row], fp16 out; writes zero row N ----------------
__global__ __launch_bounds__(256) void k_gemm1(const float* __restrict__ X, const float* __restrict__ W1,
                                               const float* __restrict__ dinv, __half* __restrict__ yh, int N){
    __shared__ float Ws[128*128];
    __shared__ float Xs[32*128];
    int t = threadIdx.x;
    int row0 = blockIdx.x * 32;
    if (blockIdx.x==0 && t < 32)
        reinterpret_cast<uint2*>(yh + (size_t)N*128)[t] = make_uint2(0u,0u);
    {
        const float4* Wg = (const float4*)W1;
        float4* Wl = (float4*)Ws;
        #pragma unroll
        for (int i=0;i<16;i++) Wl[t + i*256] = Wg[t + i*256];
    }
    {
        float4* Xl = (float4*)Xs;
        const float4* Xg = (const float4*)X;
        #pragma unroll
        for (int i=0;i<4;i++){
            int fi = t + i*256;
            int r = fi >> 5;
            float4 v = make_float4(0.f,0.f,0.f,0.f);
            if (row0 + r < N) v = Xg[(size_t)(row0+r)*32 + (fi & 31)];
            Xl[fi] = v;
        }
    }
    __syncthreads();
    int tc = t & 31, tr = t >> 5;
    float4 acc0={0,0,0,0}, acc1={0,0,0,0}, acc2={0,0,0,0}, acc3={0,0,0,0};
    for (int k=0;k<128;k+=4){
        float4 w0 = ld4(&Ws[(k+0)*128 + tc*4]);
        float4 w1 = ld4(&Ws[(k+1)*128 + tc*4]);
        float4 w2 = ld4(&Ws[(k+2)*128 + tc*4]);
        float4 w3 = ld4(&Ws[(k+3)*128 + tc*4]);
        #define ROWSTEP(ACC, RR) { float4 xr = ld4(&Xs[(4*tr+(RR))*128 + k]); \
            ACC.x += xr.x*w0.x + xr.y*w1.x + xr.z*w2.x + xr.w*w3.x; \
            ACC.y += xr.x*w0.y + xr.y*w1.y + xr.z*w2.y + xr.w*w3.y; \
            ACC.z += xr.x*w0.z + xr.y*w1.z + xr.z*w2.z + xr.w*w3.z; \
            ACC.w += xr.x*w0.w + xr.y*w1.w + xr.z*w2.w + xr.w*w3.w; }
        ROWSTEP(acc0,0) ROWSTEP(acc1,1) ROWSTEP(acc2,2) ROWSTEP(acc3,3)
        #undef ROWSTEP
    }
    #define STORESTEP(ACC, RR) { int row = row0 + 4*tr + (RR); if (row < N){ \
        float dv = dinv[row]; \
        __half2 p0 = __floats2half2_rn(ACC.x*dv, ACC.y*dv); \
        __half2 p1 = __floats2half2_rn(ACC.z*dv, ACC.w*dv); \
        uint2 stv; stv.x = *(unsigned*)&p0; stv.y = *(unsigned*)&p1; \
        *reinterpret_cast<uint2*>(&yh[(size_t)row*128 + tc*4]) = stv; } }
    STORESTEP(acc0,0) STORESTEP(acc1,1) STORESTEP(acc2,2) STORESTEP(acc3,3)
    #undef STORESTEP
}

// ---------------- layer-1 aggregation + bias + ELU + fused mean-pool atomics ----------------
__global__ void k_agg1(const __half* __restrict__ yh, const float* __restrict__ dinv,
                       const float* __restrict__ b1, const int* __restrict__ rs,
                       const int* __restrict__ csr, const int* __restrict__ batch,
                       float* __restrict__ msum, __half* __restrict__ h, int N){
    int wid = (int)((blockIdx.x * blockDim.x + threadIdx.x) >> 6);
    if (wid >= N) return;
    int lane = threadIdx.x & 63;
    int half = lane >> 5, hl = lane & 31;
    int beg = rs[wid], end = rs[wid+1];
    int len = end - beg;
    int len0 = (len + 1) >> 1;
    int hbeg = beg + (half ? len0 : 0);
    int hlen = half ? (len - len0) : len0;
    const __half* ybase = yh + hl*4;
    float4 acc = make_float4(0.f,0.f,0.f,0.f);
    if (half == 0){   // self loop once
        uint2 u = *reinterpret_cast<const uint2*>(ybase + (size_t)wid*128);
        float2 f0 = __half22float2(*(__half2*)&u.x), f1 = __half22float2(*(__half2*)&u.y);
        acc.x=f0.x; acc.y=f0.y; acc.z=f1.x; acc.w=f1.y;
    }
    int iters = (len0 + 31) >> 5;
    for (int c=0;c<iters;c++){
        int o = c*32 + hl;
        int idx = (o < hlen) ? csr[hbeg + o] : N;   // N = zero row
        int tmax = len0 - c*32; if (tmax > 32) tmax = 32;
        int nch = (tmax + 3) >> 2;                  // padded 4-chunks, no tail
        __half2 a0 = __float2half2_rn(0.f), a1 = __float2half2_rn(0.f);
        for (int ch=0; ch<nch; ++ch){
            int tb = (half<<5) + ch*4;
            int s0 = __shfl(idx, tb+0);
            int s1 = __shfl(idx, tb+1);
            int s2 = __shfl(idx, tb+2);
            int s3 = __shfl(idx, tb+3);
            uint2 u0 = *reinterpret_cast<const uint2*>(ybase + (size_t)s0*128);
            uint2 u1 = *reinterpret_cast<const uint2*>(ybase + (size_t)s1*128);
            uint2 u2 = *reinterpret_cast<const uint2*>(ybase + (size_t)s2*128);
            uint2 u3 = *reinterpret_cast<const uint2*>(ybase + (size_t)s3*128);
            a0 = __hadd2(a0, *(__half2*)&u0.x); a1 = __hadd2(a1, *(__half2*)&u0.y);
            a0 = __hadd2(a0, *(__half2*)&u1.x); a1 = __hadd2(a1, *(__half2*)&u1.y);
            a0 = __hadd2(a0, *(__half2*)&u2.x); a1 = __hadd2(a1, *(__half2*)&u2.y);
            a0 = __hadd2(a0, *(__half2*)&u3.x); a1 = __hadd2(a1, *(__half2*)&u3.y);
        }
        float2 f0 = __half22float2(a0), f1 = __half22float2(a1);
        acc.x += f0.x; acc.y += f0.y; acc.z += f1.x; acc.w += f1.y;
    }
    acc.x += __shfl_xor(acc.x, 32);
    acc.y += __shfl_xor(acc.y, 32);
    acc.z += __shfl_xor(acc.z, 32);
    acc.w += __shfl_xor(acc.w, 32);
    if (half == 0){
        float dv = dinv[wid];
        float4 bb = ld4(&b1[hl*4]);
        float4 o;
        o.x = dv*acc.x + bb.x; o.y = dv*acc.y + bb.y;
        o.z = dv*acc.z + bb.z; o.w = dv*acc.w + bb.w;
        o.x = o.x > 0.f ? o.x : expm1f(o.x);
        o.y = o.y > 0.f ? o.y : expm1f(o.y);
        o.z = o.z > 0.f ? o.z : expm1f(o.z);
        o.w = o.w > 0.f ? o.w : expm1f(o.w);
        __half2 p0 = __floats2half2_rn(o.x, o.y);
        __half2 p1 = __floats2half2_rn(o.z, o.w);
        uint2 stv; stv.x = *(unsigned*)&p0; stv.y = *(unsigned*)&p1;
        *reinterpret_cast<uint2*>(&h[(size_t)wid*128 + hl*4]) = stv;
        int g = batch[wid];
        float* mp = &msum[g*128 + hl*4];
        atomicAdd(mp+0, o.x); atomicAdd(mp+1, o.y);
        atomicAdd(mp+2, o.z); atomicAdd(mp+3, o.w);
    }
}

__global__ void k_mlp1(const float* __restrict__ msum, const int* __restrict__ gstart,
                       const float* __restrict__ mW1, const float* __restrict__ mb1,
                       float* __restrict__ r1){
    int g = blockIdx.x, c = threadIdx.x;   // 128 threads
    int cnt = gstart[g+1] - gstart[g];
    float inv = 1.f / (float)(cnt > 1 ? cnt : 1);
    float acc = mb1[c];
    for (int k=0;k<128;k++) acc = fmaf(msum[g*128+k]*inv, mW1[k*128+c], acc);
    r1[g*128+c] = fmaxf(acc, 0.f);
}

__global__ void k_mlp2(const float* __restrict__ msum2, const int* __restrict__ gstart,
                       const float* __restrict__ mW2, const float* __restrict__ mb2,
                       float* __restrict__ r2){
    int g = blockIdx.x, c = threadIdx.x;
    if (c >= 32) return;
    int cnt = gstart[g+1] - gstart[g];
    float inv = 1.f / (float)(cnt > 1 ? cnt : 1);
    float acc = mb2[c];
    for (int k=0;k<32;k++) acc = fmaf(msum2[g*32+k]*inv, mW2[k*32+c], acc);
    r2[g*32+c] = fmaxf(acc, 0.f);
}

// ---------------- GEMM2: y2 = ((h + r1[batch]) @ W2) * dinv, fp16 in/out ----------------
__global__ __launch_bounds__(256) void k_gemm2(const __half* __restrict__ h, const float* __restrict__ vn,
                                               const int* __restrict__ batch, const float* __restrict__ W2,
                                               const float* __restrict__ dinv, __half* __restrict__ y2, int N){
    __shared__ float W2s[128*32];
    int t = threadIdx.x;
    if (blockIdx.x==0 && t < 8)
        reinterpret_cast<uint2*>(y2 + (size_t)N*32)[t] = make_uint2(0u,0u);
    {
        float4* Wl = (float4*)W2s;
        const float4* Wg = (const float4*)W2;
        #pragma unroll
        for (int i=0;i<4;i++) Wl[t + i*256] = Wg[t + i*256];
    }
    __syncthreads();
    int row0 = blockIdx.x*64;
    int tc = t & 7, trg = t >> 3;
    int ra = row0 + 2*trg, rb = ra + 1;
    bool oka = ra < N, okb = rb < N;
    const __half* hpa = h + (size_t)(oka ? ra : 0)*128;
    const __half* hpb = h + (size_t)(okb ? rb : 0)*128;
    const float* vpa = vn + (size_t)(oka ? batch[ra] : 0)*128;
    const float* vpb = vn + (size_t)(okb ? batch[rb] : 0)*128;
    float4 acca={0,0,0,0}, accb={0,0,0,0};
    for (int k=0;k<128;k+=4){
        float4 w0 = ld4(&W2s[(k+0)*32 + tc*4]);
        float4 w1 = ld4(&W2s[(k+1)*32 + tc*4]);
        float4 w2 = ld4(&W2s[(k+2)*32 + tc*4]);
        float4 w3 = ld4(&W2s[(k+3)*32 + tc*4]);
        {
            uint2 u = *reinterpret_cast<const uint2*>(&hpa[k]);
            float2 f0 = __half22float2(*(__half2*)&u.x), f1 = __half22float2(*(__half2*)&u.y);
            float4 bb = ld4(vpa + k);
            float ax=f0.x+bb.x, ay=f0.y+bb.y, az=f1.x+bb.z, aw=f1.y+bb.w;
            acca.x += ax*w0.x + ay*w1.x + az*w2.x + aw*w3.x;
            acca.y += ax*w0.y + ay*w1.y + az*w2.y + aw*w3.y;
            acca.z += ax*w0.z + ay*w1.z + az*w2.z + aw*w3.z;
            acca.w += ax*w0.w + ay*w1.w + az*w2.w + aw*w3.w;
        }
        {
            uint2 u = *reinterpret_cast<const uint2*>(&hpb[k]);
            float2 f0 = __half22float2(*(__half2*)&u.x), f1 = __half22float2(*(__half2*)&u.y);
            float4 bb = ld4(vpb + k);
            float ax=f0.x+bb.x, ay=f0.y+bb.y, az=f1.x+bb.z, aw=f1.y+bb.w;
            accb.x += ax*w0.x + ay*w1.x + az*w2.x + aw*w3.x;
            accb.y += ax*w0.y + ay*w1.y + az*w2.y + aw*w3.y;
            accb.z += ax*w0.z + ay*w1.z + az*w2.z + aw*w3.z;
            accb.w += ax*w0.w + ay*w1.w + az*w2.w + aw*w3.w;
        }
    }
    if (oka){
        float dv = dinv[ra];
        __half2 p0 = __floats2half2_rn(acca.x*dv, acca.y*dv);
        __half2 p1 = __floats2half2_rn(acca.z*dv, acca.w*dv);
        uint2 stv; stv.x = *(unsigned*)&p0; stv.y = *(unsigned*)&p1;
        *reinterpret_cast<uint2*>(&y2[(size_t)ra*32 + tc*4]) = stv;
    }
    if (okb){
        float dv = dinv[rb];
        __half2 p0 = __floats2half2_rn(accb.x*dv, accb.y*dv);
        __half2 p1 = __floats2half2_rn(accb.z*dv, accb.w*dv);
        uint2 stv; stv.x = *(unsigned*)&p0; stv.y = *(unsigned*)&p1;
        *reinterpret_cast<uint2*>(&y2[(size_t)rb*32 + tc*4]) = stv;
    }
}

// ---------------- layer-2 aggregation + bias + fused mean-pool atomics ----------------
__global__ void k_agg2h(const __half* __restrict__ y2, const float* __restrict__ dinv,
                        const float* __restrict__ b2, const int* __restrict__ rs,
                        const int* __restrict__ csr, const int* __restrict__ batch,
                        float* __restrict__ msum2, float* __restrict__ Z, int N){
    int wid = (int)((blockIdx.x*blockDim.x + threadIdx.x) >> 6);
    if (wid >= N) return;
    int lane = threadIdx.x & 63;
    int q = lane >> 4, ql = lane & 15;
    int beg = rs[wid], end = rs[wid+1], len = end-beg;
    int qlen = (len + 3) >> 2;
    int qbeg = beg + q*qlen;
    int qend = qbeg + qlen; if (qend > end) qend = end;
    int mylen = qend - qbeg; if (mylen < 0) mylen = 0;
    const __half2* ybase = (const __half2*)(y2) + ql;
    float sx = 0.f, sy = 0.f;
    int iters = (qlen + 15) >> 4;
    for (int c=0;c<iters;c++){
        int o = c*16 + ql;
        int idx = (o < mylen) ? csr[qbeg + o] : N;
        int tmax = qlen - c*16; if (tmax > 16) tmax = 16;
        int nch = (tmax + 3) >> 2;
        __half2 a = __float2half2_rn(0.f);
        for (int ch=0; ch<nch; ++ch){
            int tb = (q<<4) + ch*4;
            int s0 = __shfl(idx, tb+0);
            int s1 = __shfl(idx, tb+1);
            int s2 = __shfl(idx, tb+2);
            int s3 = __shfl(idx, tb+3);
            __half2 v0 = ybase[(size_t)s0*16];
            __half2 v1 = ybase[(size_t)s1*16];
            __half2 v2 = ybase[(size_t)s2*16];
            __half2 v3 = ybase[(size_t)s3*16];
            a = __hadd2(a, v0); a = __hadd2(a, v1);
            a = __hadd2(a, v2); a = __hadd2(a, v3);
        }
        float2 f = __half22float2(a);
        sx += f.x; sy += f.y;
    }
    sx += __shfl_xor(sx, 16); sy += __shfl_xor(sy, 16);
    sx += __shfl_xor(sx, 32); sy += __shfl_xor(sy, 32);
    if (q==0){
        float2 self = __half22float2(ybase[(size_t)wid*16]);
        sx += self.x; sy += self.y;
        float dv = dinv[wid];
        float2 o;
        o.x = dv*sx + b2[ql*2];
        o.y = dv*sy + b2[ql*2+1];
        *reinterpret_cast<float2*>(&Z[(size_t)wid*32 + ql*2]) = o;
        int g = batch[wid];
        atomicAdd(&msum2[g*32 + ql*2], o.x);
        atomicAdd(&msum2[g*32 + ql*2+1], o.y);
    }
}

// ---------------- + virtual node + softmax (in-place on d_out) ----------------
__global__ void k_softmax(float* __restrict__ Z, const float* __restrict__ r2,
                          const int* __restrict__ batch, int N){
    int r = blockIdx.x*8 + (threadIdx.x>>5);
    int c = threadIdx.x & 31;
    if (r >= N) return;
    float z = Z[(size_t)r*32+c] + r2[batch[r]*32 + c];
    float m = z;
    #pragma unroll
    for (int off=16; off>=1; off>>=1) m = fmaxf(m, __shfl_xor(m, off));
    float e = expf(z - m);
    float s = e;
    #pragma unroll
    for (int off=16; off>=1; off>>=1) s += __shfl_xor(s, off);
    Z[(size_t)r*32+c] = e / s;
}

extern "C" void kernel_launch(void* const* d_in, const int* in_sizes, int n_in,
                              void* d_out, int out_size, void* d_ws, size_t ws_size,
                              hipStream_t stream){
    const float* X   = (const float*)d_in[0];
    const float* W1  = (const float*)d_in[1];
    const float* b1  = (const float*)d_in[2];
    const float* W2  = (const float*)d_in[3];
    const float* b2  = (const float*)d_in[4];
    const float* mW1 = (const float*)d_in[5];
    const float* mb1 = (const float*)d_in[6];
    const float* mW2 = (const float*)d_in[7];
    const float* mb2 = (const float*)d_in[8];
    const int*   ei  = (const int*)d_in[9];
    const int*   batch = (const int*)d_in[10];
    int N = in_sizes[0] / 128;
    int E = in_sizes[9] / 2;
    const int* src = ei;
    const int* dst = ei + E;
    float* Zout = (float*)d_out;

    char* wsp = (char*)d_ws;
    size_t off = 0;
    auto alloc = [&](size_t bytes)->char*{
        char* p = wsp + off; off += (bytes + 255) & ~(size_t)255; return p;
    };
    // zero zone
    int*   bcnt  = (int*)  alloc((size_t)MAXNB*4);
    int*   bfill = (int*)  alloc((size_t)MAXNB*4);
    float* msum  = (float*)alloc((size_t)GNUM*128*4);
    float* msum2 = (float*)alloc((size_t)GNUM*32*4);
    size_t zero_bytes = off;
    // rest
    int*   bbase = (int*)  alloc((size_t)(MAXNB+1)*4);
    int*   rs    = (int*)  alloc((size_t)(N+1)*4);
    int*   gstart= (int*)  alloc((GNUM+1)*4);
    unsigned* ebuf = (unsigned*)alloc((size_t)E*4);
    int*   csr   = (int*)  alloc((size_t)E*4);
    float* dinvp = (float*)alloc((size_t)N*4);
    __half* yh   = (__half*)alloc((size_t)(N+1)*128*2);   // +1: zero row
    __half* h    = (__half*)alloc((size_t)N*128*2);
    __half* y2h  = (__half*)alloc((size_t)(N+1)*32*2);    // +1: zero row
    float* r1buf = (float*)alloc((size_t)GNUM*128*4);
    float* r2buf = (float*)alloc((size_t)GNUM*32*4);
    (void)ws_size; (void)n_in; (void)out_size;

    hipMemsetAsync(d_ws, 0, zero_bytes, stream);

    int NB = (N + 127) >> 7;            // 391
    int EB = (E + CHUNK-1) / CHUNK;     // 391

    k_hist         <<<EB, 256, 0, stream>>>(dst, E, NB, bcnt);
    k_scan1b       <<<1, 256, 0, stream>>>(bcnt, bbase, NB, E, batch, N, gstart);
    k_scatter      <<<EB, 256, 0, stream>>>(src, dst, E, NB, bbase, bfill, ebuf);
    k_bucket_finish<<<NB, 256, 0, stream>>>(ebuf, bbase, rs, csr, dinvp, N, E);

    k_gemm1 <<<(N+31)/32, 256, 0, stream>>>(X, W1, dinvp, yh, N);
    k_agg1  <<<(N+3)/4, 256, 0, stream>>>(yh, dinvp, b1, rs, csr, batch, msum, h, N);
    k_mlp1  <<<GNUM, 128, 0, stream>>>(msum, gstart, mW1, mb1, r1buf);

    k_gemm2 <<<(N+63)/64, 256, 0, stream>>>(h, r1buf, batch, W2, dinvp, y2h, N);
    k_agg2h <<<(N+3)/4, 256, 0, stream>>>(y2h, dinvp, b2, rs, csr, batch, msum2, Zout, N);
    k_mlp2  <<<GNUM, 64, 0, stream>>>(msum2, gstart, mW2, mb2, r2buf);
    k_softmax<<<(N+7)/8, 256, 0, stream>>>(Zout, r2buf, batch, N);
}

// Round 7
// 259.718 us; speedup vs baseline: 2.0219x; 2.0219x over previous
//
#include <hip/hip_runtime.h>
#include <hip/hip_bf16.h>
#include <hip/hip_fp16.h>

#define DEV_INLINE __device__ __forceinline__

static DEV_INLINE float4 ld4(const float* p){ return *reinterpret_cast<const float4*>(p); }

#define GNUM 64
#define CHUNK 4096
#define MAXNB 1024   // bucket = dst>>7; N <= 65536 (u16 packing)

// ======================= bucketed edge build =======================
__global__ __launch_bounds__(256) void k_hist(const int* __restrict__ dst, int E, int NB,
                                              int* __restrict__ bcnt){
    __shared__ int cnt[MAXNB];
    int t = threadIdx.x; int base0 = blockIdx.x*CHUNK;
    for (int i=t;i<NB;i+=256) cnt[i]=0;
    __syncthreads();
    int tot = E - base0; if (tot > CHUNK) tot = CHUNK;
    #pragma unroll
    for (int k=0;k<16;k++){
        int o = t + k*256;
        if (o < tot) atomicAdd(&cnt[dst[base0+o]>>7], 1);
    }
    __syncthreads();
    for (int i=t;i<NB;i+=256) if (cnt[i]) atomicAdd(&bcnt[i], cnt[i]);
}

// one-block exclusive scan (M<=1024) + fused graph-boundary binary search
__global__ void k_scan1b(const int* __restrict__ in, int* __restrict__ out, int M, int total,
                         const int* __restrict__ batch, int N, int* __restrict__ gstart){
    __shared__ int ws[4];
    int t = threadIdx.x;
    int i0 = t*4;
    int c0=(i0+0<M)?in[i0+0]:0, c1=(i0+1<M)?in[i0+1]:0;
    int c2=(i0+2<M)?in[i0+2]:0, c3=(i0+3<M)?in[i0+3]:0;
    int tsum=c0+c1+c2+c3;
    int lane=t&63, w=t>>6;
    int x=tsum;
    for (int off=1;off<64;off<<=1){ int yv=__shfl_up(x,off); if (lane>=off) x+=yv; }
    if (lane==63) ws[w]=x;
    __syncthreads();
    if (t==0){ int a=0; for (int i=0;i<4;i++){ int tmp=ws[i]; ws[i]=a; a+=tmp; } }
    __syncthreads();
    int ex = x - tsum + ws[w];
    if (i0+0<M) out[i0+0]=ex; ex+=c0;
    if (i0+1<M) out[i0+1]=ex; ex+=c1;
    if (i0+2<M) out[i0+2]=ex; ex+=c2;
    if (i0+3<M) out[i0+3]=ex;
    if (t==0 && total>=0) out[M]=total;
    // fused: graph boundaries (batch sorted)
    if (t <= GNUM){
        int lo = 0, hi = N;
        while (lo < hi){ int mid = (lo+hi)>>1; if (batch[mid] < t) lo = mid+1; else hi = mid; }
        gstart[t] = lo;
    }
}

__global__ __launch_bounds__(256) void k_scatter(const int* __restrict__ src, const int* __restrict__ dst,
                                                 int E, int NB, const int* __restrict__ bbase,
                                                 int* __restrict__ bfill, unsigned* __restrict__ ebuf){
    __shared__ int cnt[MAXNB];
    __shared__ int pfx[MAXNB];
    __shared__ int gbase[MAXNB];
    __shared__ unsigned stage[CHUNK];
    __shared__ int ws[4];
    int t = threadIdx.x; int base0 = blockIdx.x*CHUNK;
    int tot = E - base0; if (tot > CHUNK) tot = CHUNK;
    for (int i=t;i<NB;i+=256) cnt[i]=0;
    __syncthreads();
    unsigned v[16]; int rk[16];
    #pragma unroll
    for (int k=0;k<16;k++){
        int o = t + k*256;
        if (o < tot){
            int e = base0 + o;
            int s = src[e], d = dst[e];
            v[k] = (unsigned)s | ((unsigned)d<<16);
            rk[k] = atomicAdd(&cnt[d>>7], 1);
        } else { v[k]=0u; rk[k]=-1; }
    }
    __syncthreads();
    int i0 = t*4;
    int c0=(i0+0<NB)?cnt[i0+0]:0, c1=(i0+1<NB)?cnt[i0+1]:0;
    int c2=(i0+2<NB)?cnt[i0+2]:0, c3=(i0+3<NB)?cnt[i0+3]:0;
    int tsum=c0+c1+c2+c3;
    int lane=t&63, w=t>>6;
    int x=tsum;
    for (int off=1;off<64;off<<=1){ int yv=__shfl_up(x,off); if (lane>=off) x+=yv; }
    if (lane==63) ws[w]=x;
    __syncthreads();
    if (t==0){ int a=0; for (int i=0;i<4;i++){ int tmp=ws[i]; ws[i]=a; a+=tmp; } }
    __syncthreads();
    int ex = x - tsum + ws[w];
    if (i0+0<NB) pfx[i0+0]=ex; ex+=c0;
    if (i0+1<NB) pfx[i0+1]=ex; ex+=c1;
    if (i0+2<NB) pfx[i0+2]=ex; ex+=c2;
    if (i0+3<NB) pfx[i0+3]=ex;
    __syncthreads();
    for (int i=t;i<NB;i+=256){
        int c = cnt[i];
        gbase[i] = c ? (bbase[i] + atomicAdd(&bfill[i], c)) : 0;
    }
    __syncthreads();
    #pragma unroll
    for (int k=0;k<16;k++) if (rk[k]>=0){ int b = (int)(v[k]>>23); stage[pfx[b]+rk[k]] = v[k]; }
    __syncthreads();
    for (int j=t;j<tot;j+=256){
        unsigned u = stage[j];
        int b = (int)(u>>23);
        ebuf[gbase[b] + (j - pfx[b])] = u;
    }
}

// fused: per-bucket degree count -> in-LDS prefix -> rs + dinv -> CSR fill
__global__ __launch_bounds__(256) void k_bucket_finish(const unsigned* __restrict__ ebuf,
                                                       const int* __restrict__ bbase,
                                                       int* __restrict__ rs, int* __restrict__ csr,
                                                       float* __restrict__ dinv, int N, int E){
    __shared__ int c2[128];
    __shared__ int rsl[128];
    __shared__ int ws[4];
    int b = blockIdx.x, t = threadIdx.x;
    if (t < 128) c2[t] = 0;
    __syncthreads();
    int s0 = bbase[b], s1 = bbase[b+1];
    for (int j = s0+t; j < s1; j += 256)
        atomicAdd(&c2[(ebuf[j]>>16)&127], 1);
    __syncthreads();
    int v = (t < 128) ? c2[t] : 0;
    int lane = t & 63, w = t >> 6;
    int x = v;
    for (int off=1; off<64; off<<=1){
        int yv = __shfl_up(x, off);
        if (lane >= off) x += yv;
    }
    if (lane == 63) ws[w] = x;
    __syncthreads();
    if (t < 128){
        int ex = x - v + ((w == 1) ? ws[0] : 0);
        rsl[t] = s0 + ex;
        int node = (b<<7) + t;
        if (node < N){
            rs[node] = s0 + ex;
            dinv[node] = rsqrtf((float)(v + 1));
        }
    }
    if (b == (int)gridDim.x - 1 && t == 0) rs[N] = E;
    __syncthreads();
    if (t < 128) c2[t] = 0;
    __syncthreads();
    for (int j = s0+t; j < s1; j += 256){
        unsigned u = ebuf[j];
        int ld = (u>>16)&127;
        int p = atomicAdd(&c2[ld], 1);
        csr[rsl[ld]+p] = (int)(u & 0xffffu);
    }
}

// ---------------- GEMM1: y = (X @ W1) * dinv[row], fp16 out; writes zero row N ----------------
__global__ __launch_bounds__(256) void k_gemm1(const float* __restrict__ X, const float* __restrict__ W1,
                                               const float* __restrict__ dinv, __half* __restrict__ yh, int N){
    __shared__ float Ws[128*128];
    __shared__ float Xs[32*128];
    int t = threadIdx.x;
    int row0 = blockIdx.x * 32;
    if (blockIdx.x==0 && t < 32)
        reinterpret_cast<uint2*>(yh + (size_t)N*128)[t] = make_uint2(0u,0u);
    {
        const float4* Wg = (const float4*)W1;
        float4* Wl = (float4*)Ws;
        #pragma unroll
        for (int i=0;i<16;i++) Wl[t + i*256] = Wg[t + i*256];
    }
    {
        float4* Xl = (float4*)Xs;
        const float4* Xg = (const float4*)X;
        #pragma unroll
        for (int i=0;i<4;i++){
            int fi = t + i*256;
            int r = fi >> 5;
            float4 v = make_float4(0.f,0.f,0.f,0.f);
            if (row0 + r < N) v = Xg[(size_t)(row0+r)*32 + (fi & 31)];
            Xl[fi] = v;
        }
    }
    __syncthreads();
    int tc = t & 31, tr = t >> 5;
    float4 acc0={0,0,0,0}, acc1={0,0,0,0}, acc2={0,0,0,0}, acc3={0,0,0,0};
    for (int k=0;k<128;k+=4){
        float4 w0 = ld4(&Ws[(k+0)*128 + tc*4]);
        float4 w1 = ld4(&Ws[(k+1)*128 + tc*4]);
        float4 w2 = ld4(&Ws[(k+2)*128 + tc*4]);
        float4 w3 = ld4(&Ws[(k+3)*128 + tc*4]);
        #define ROWSTEP(ACC, RR) { float4 xr = ld4(&Xs[(4*tr+(RR))*128 + k]); \
            ACC.x += xr.x*w0.x + xr.y*w1.x + xr.z*w2.x + xr.w*w3.x; \
            ACC.y += xr.x*w0.y + xr.y*w1.y + xr.z*w2.y + xr.w*w3.y; \
            ACC.z += xr.x*w0.z + xr.y*w1.z + xr.z*w2.z + xr.w*w3.z; \
            ACC.w += xr.x*w0.w + xr.y*w1.w + xr.z*w2.w + xr.w*w3.w; }
        ROWSTEP(acc0,0) ROWSTEP(acc1,1) ROWSTEP(acc2,2) ROWSTEP(acc3,3)
        #undef ROWSTEP
    }
    #define STORESTEP(ACC, RR) { int row = row0 + 4*tr + (RR); if (row < N){ \
        float dv = dinv[row]; \
        __half2 p0 = __floats2half2_rn(ACC.x*dv, ACC.y*dv); \
        __half2 p1 = __floats2half2_rn(ACC.z*dv, ACC.w*dv); \
        uint2 stv; stv.x = *(unsigned*)&p0; stv.y = *(unsigned*)&p1; \
        *reinterpret_cast<uint2*>(&yh[(size_t)row*128 + tc*4]) = stv; } }
    STORESTEP(acc0,0) STORESTEP(acc1,1) STORESTEP(acc2,2) STORESTEP(acc3,3)
    #undef STORESTEP
}

// ---------------- layer-1 aggregation: wave/node, zero-row, fp16 pair accum, 4x ILP ----------------
__global__ void k_agg1(const __half* __restrict__ yh, const float* __restrict__ dinv,
                       const float* __restrict__ b1, const int* __restrict__ rs,
                       const int* __restrict__ csr, __half* __restrict__ h, int N){
    int wid = (int)((blockIdx.x * blockDim.x + threadIdx.x) >> 6);
    if (wid >= N) return;
    int lane = threadIdx.x & 63;
    int half = lane >> 5, hl = lane & 31;
    int beg = rs[wid], end = rs[wid+1];
    int len = end - beg;
    int len0 = (len + 1) >> 1;
    int hbeg = beg + (half ? len0 : 0);
    int hlen = half ? (len - len0) : len0;
    const __half* ybase = yh + hl*4;
    float4 acc = make_float4(0.f,0.f,0.f,0.f);
    if (half == 0){   // self loop once
        uint2 u = *reinterpret_cast<const uint2*>(ybase + (size_t)wid*128);
        float2 f0 = __half22float2(*(__half2*)&u.x), f1 = __half22float2(*(__half2*)&u.y);
        acc.x=f0.x; acc.y=f0.y; acc.z=f1.x; acc.w=f1.y;
    }
    int iters = (len0 + 31) >> 5;
    for (int c=0;c<iters;c++){
        int o = c*32 + hl;
        int idx = (o < hlen) ? csr[hbeg + o] : N;   // N = zero row
        int tmax = len0 - c*32; if (tmax > 32) tmax = 32;
        int nch = (tmax + 3) >> 2;                  // padded 4-chunks, no tail
        __half2 a0 = __float2half2_rn(0.f), a1 = __float2half2_rn(0.f);
        for (int ch=0; ch<nch; ++ch){
            int tb = (half<<5) + ch*4;
            int s0 = __shfl(idx, tb+0);
            int s1 = __shfl(idx, tb+1);
            int s2 = __shfl(idx, tb+2);
            int s3 = __shfl(idx, tb+3);
            uint2 u0 = *reinterpret_cast<const uint2*>(ybase + (size_t)s0*128);
            uint2 u1 = *reinterpret_cast<const uint2*>(ybase + (size_t)s1*128);
            uint2 u2 = *reinterpret_cast<const uint2*>(ybase + (size_t)s2*128);
            uint2 u3 = *reinterpret_cast<const uint2*>(ybase + (size_t)s3*128);
            a0 = __hadd2(a0, *(__half2*)&u0.x); a1 = __hadd2(a1, *(__half2*)&u0.y);
            a0 = __hadd2(a0, *(__half2*)&u1.x); a1 = __hadd2(a1, *(__half2*)&u1.y);
            a0 = __hadd2(a0, *(__half2*)&u2.x); a1 = __hadd2(a1, *(__half2*)&u2.y);
            a0 = __hadd2(a0, *(__half2*)&u3.x); a1 = __hadd2(a1, *(__half2*)&u3.y);
        }
        float2 f0 = __half22float2(a0), f1 = __half22float2(a1);
        acc.x += f0.x; acc.y += f0.y; acc.z += f1.x; acc.w += f1.y;
    }
    acc.x += __shfl_xor(acc.x, 32);
    acc.y += __shfl_xor(acc.y, 32);
    acc.z += __shfl_xor(acc.z, 32);
    acc.w += __shfl_xor(acc.w, 32);
    if (half == 0){
        float dv = dinv[wid];
        float4 bb = ld4(&b1[hl*4]);
        float4 o;
        o.x = dv*acc.x + bb.x; o.y = dv*acc.y + bb.y;
        o.z = dv*acc.z + bb.z; o.w = dv*acc.w + bb.w;
        o.x = o.x > 0.f ? o.x : expm1f(o.x);
        o.y = o.y > 0.f ? o.y : expm1f(o.y);
        o.z = o.z > 0.f ? o.z : expm1f(o.z);
        o.w = o.w > 0.f ? o.w : expm1f(o.w);
        __half2 p0 = __floats2half2_rn(o.x, o.y);
        __half2 p1 = __floats2half2_rn(o.z, o.w);
        uint2 stv; stv.x = *(unsigned*)&p0; stv.y = *(unsigned*)&p1;
        *reinterpret_cast<uint2*>(&h[(size_t)wid*128 + hl*4]) = stv;
    }
}

// ---------------- mean-pool partial sums (streaming, few atomics) ----------------
__global__ void k_mpoolh(const __half* __restrict__ hsrc, const int* __restrict__ gstart,
                         float* __restrict__ msum){
    int g = blockIdx.x, part = blockIdx.y, P = gridDim.y;
    int c = threadIdx.x;   // 64 threads, half2 cols
    int s0 = gstart[g], s1 = gstart[g+1];
    int len = s1 - s0;
    int per = (len + P - 1) / P;
    int rbeg = s0 + part*per, rend = rbeg + per; if (rend > s1) rend = s1;
    float sx = 0.f, sy = 0.f;
    const __half2* h2 = (const __half2*)hsrc;
    for (int r = rbeg; r < rend; ++r){
        float2 f = __half22float2(h2[(size_t)r*64 + c]);
        sx += f.x; sy += f.y;
    }
    if (rend > rbeg){
        atomicAdd(&msum[g*128 + 2*c], sx);
        atomicAdd(&msum[g*128 + 2*c+1], sy);
    }
}

__global__ void k_mpool(const float* __restrict__ srcm, const int* __restrict__ gstart,
                        float* __restrict__ msum, int C){
    int g = blockIdx.x, part = blockIdx.y, P = gridDim.y;
    int c = threadIdx.x;
    if (c >= C) return;
    int s0 = gstart[g], s1 = gstart[g+1];
    int len = s1 - s0;
    int per = (len + P - 1) / P;
    int rbeg = s0 + part*per, rend = rbeg + per; if (rend > s1) rend = s1;
    float sum = 0.f;
    for (int r = rbeg; r < rend; ++r) sum += srcm[(size_t)r*C + c];
    if (rend > rbeg) atomicAdd(&msum[g*C + c], sum);
}

__global__ void k_mlp1(const float* __restrict__ msum, const int* __restrict__ gstart,
                       const float* __restrict__ mW1, const float* __restrict__ mb1,
                       float* __restrict__ r1){
    int g = blockIdx.x, c = threadIdx.x;   // 128 threads
    int cnt = gstart[g+1] - gstart[g];
    float inv = 1.f / (float)(cnt > 1 ? cnt : 1);
    float acc = mb1[c];
    for (int k=0;k<128;k++) acc = fmaf(msum[g*128+k]*inv, mW1[k*128+c], acc);
    r1[g*128+c] = fmaxf(acc, 0.f);
}

__global__ void k_mlp2(const float* __restrict__ msum2, const int* __restrict__ gstart,
                       const float* __restrict__ mW2, const float* __restrict__ mb2,
                       float* __restrict__ r2){
    int g = blockIdx.x, c = threadIdx.x;
    if (c >= 32) return;
    int cnt = gstart[g+1] - gstart[g];
    float inv = 1.f / (float)(cnt > 1 ? cnt : 1);
    float acc = mb2[c];
    for (int k=0;k<32;k++) acc = fmaf(msum2[g*32+k]*inv, mW2[k*32+c], acc);
    r2[g*32+c] = fmaxf(acc, 0.f);
}

// ---------------- GEMM2: y2 = ((h + r1[batch]) @ W2) * dinv, fp16 in/out ----------------
__global__ __launch_bounds__(256) void k_gemm2(const __half* __restrict__ h, const float* __restrict__ vn,
                                               const int* __restrict__ batch, const float* __restrict__ W2,
                                               const float* __restrict__ dinv, __half* __restrict__ y2, int N){
    __shared__ float W2s[128*32];
    int t = threadIdx.x;
    if (blockIdx.x==0 && t < 8)
        reinterpret_cast<uint2*>(y2 + (size_t)N*32)[t] = make_uint2(0u,0u);
    {
        float4* Wl = (float4*)W2s;
        const float4* Wg = (const float4*)W2;
        #pragma unroll
        for (int i=0;i<4;i++) Wl[t + i*256] = Wg[t + i*256];
    }
    __syncthreads();
    int row0 = blockIdx.x*64;
    int tc = t & 7, trg = t >> 3;
    int ra = row0 + 2*trg, rb = ra + 1;
    bool oka = ra < N, okb = rb < N;
    const __half* hpa = h + (size_t)(oka ? ra : 0)*128;
    const __half* hpb = h + (size_t)(okb ? rb : 0)*128;
    const float* vpa = vn + (size_t)(oka ? batch[ra] : 0)*128;
    const float* vpb = vn + (size_t)(okb ? batch[rb] : 0)*128;
    float4 acca={0,0,0,0}, accb={0,0,0,0};
    for (int k=0;k<128;k+=4){
        float4 w0 = ld4(&W2s[(k+0)*32 + tc*4]);
        float4 w1 = ld4(&W2s[(k+1)*32 + tc*4]);
        float4 w2 = ld4(&W2s[(k+2)*32 + tc*4]);
        float4 w3 = ld4(&W2s[(k+3)*32 + tc*4]);
        {
            uint2 u = *reinterpret_cast<const uint2*>(&hpa[k]);
            float2 f0 = __half22float2(*(__half2*)&u.x), f1 = __half22float2(*(__half2*)&u.y);
            float4 bb = ld4(vpa + k);
            float ax=f0.x+bb.x, ay=f0.y+bb.y, az=f1.x+bb.z, aw=f1.y+bb.w;
            acca.x += ax*w0.x + ay*w1.x + az*w2.x + aw*w3.x;
            acca.y += ax*w0.y + ay*w1.y + az*w2.y + aw*w3.y;
            acca.z += ax*w0.z + ay*w1.z + az*w2.z + aw*w3.z;
            acca.w += ax*w0.w + ay*w1.w + az*w2.w + aw*w3.w;
        }
        {
            uint2 u = *reinterpret_cast<const uint2*>(&hpb[k]);
            float2 f0 = __half22float2(*(__half2*)&u.x), f1 = __half22float2(*(__half2*)&u.y);
            float4 bb = ld4(vpb + k);
            float ax=f0.x+bb.x, ay=f0.y+bb.y, az=f1.x+bb.z, aw=f1.y+bb.w;
            accb.x += ax*w0.x + ay*w1.x + az*w2.x + aw*w3.x;
            accb.y += ax*w0.y + ay*w1.y + az*w2.y + aw*w3.y;
            accb.z += ax*w0.z + ay*w1.z + az*w2.z + aw*w3.z;
            accb.w += ax*w0.w + ay*w1.w + az*w2.w + aw*w3.w;
        }
    }
    if (oka){
        float dv = dinv[ra];
        __half2 p0 = __floats2half2_rn(acca.x*dv, acca.y*dv);
        __half2 p1 = __floats2half2_rn(acca.z*dv, acca.w*dv);
        uint2 stv; stv.x = *(unsigned*)&p0; stv.y = *(unsigned*)&p1;
        *reinterpret_cast<uint2*>(&y2[(size_t)ra*32 + tc*4]) = stv;
    }
    if (okb){
        float dv = dinv[rb];
        __half2 p0 = __floats2half2_rn(accb.x*dv, accb.y*dv);
        __half2 p1 = __floats2half2_rn(accb.z*dv, accb.w*dv);
        uint2 stv; stv.x = *(unsigned*)&p0; stv.y = *(unsigned*)&p1;
        *reinterpret_cast<uint2*>(&y2[(size_t)rb*32 + tc*4]) = stv;
    }
}

// ---------------- layer-2 aggregation: quarter-wave, zero-row, fp16 accum ----------------
__global__ void k_agg2h(const __half* __restrict__ y2, const float* __restrict__ dinv,
                        const float* __restrict__ b2, const int* __restrict__ rs,
                        const int* __restrict__ csr, float* __restrict__ Z, int N){
    int wid = (int)((blockIdx.x*blockDim.x + threadIdx.x) >> 6);
    if (wid >= N) return;
    int lane = threadIdx.x & 63;
    int q = lane >> 4, ql = lane & 15;
    int beg = rs[wid], end = rs[wid+1], len = end-beg;
    int qlen = (len + 3) >> 2;
    int qbeg = beg + q*qlen;
    int qend = qbeg + qlen; if (qend > end) qend = end;
    int mylen = qend - qbeg; if (mylen < 0) mylen = 0;
    const __half2* ybase = (const __half2*)(y2) + ql;
    float sx = 0.f, sy = 0.f;
    int iters = (qlen + 15) >> 4;
    for (int c=0;c<iters;c++){
        int o = c*16 + ql;
        int idx = (o < mylen) ? csr[qbeg + o] : N;
        int tmax = qlen - c*16; if (tmax > 16) tmax = 16;
        int nch = (tmax + 3) >> 2;
        __half2 a = __float2half2_rn(0.f);
        for (int ch=0; ch<nch; ++ch){
            int tb = (q<<4) + ch*4;
            int s0 = __shfl(idx, tb+0);
            int s1 = __shfl(idx, tb+1);
            int s2 = __shfl(idx, tb+2);
            int s3 = __shfl(idx, tb+3);
            __half2 v0 = ybase[(size_t)s0*16];
            __half2 v1 = ybase[(size_t)s1*16];
            __half2 v2 = ybase[(size_t)s2*16];
            __half2 v3 = ybase[(size_t)s3*16];
            a = __hadd2(a, v0); a = __hadd2(a, v1);
            a = __hadd2(a, v2); a = __hadd2(a, v3);
        }
        float2 f = __half22float2(a);
        sx += f.x; sy += f.y;
    }
    sx += __shfl_xor(sx, 16); sy += __shfl_xor(sy, 16);
    sx += __shfl_xor(sx, 32); sy += __shfl_xor(sy, 32);
    if (q==0){
        float2 self = __half22float2(ybase[(size_t)wid*16]);
        sx += self.x; sy += self.y;
        float dv = dinv[wid];
        float2 o;
        o.x = dv*sx + b2[ql*2];
        o.y = dv*sy + b2[ql*2+1];
        *reinterpret_cast<float2*>(&Z[(size_t)wid*32 + ql*2]) = o;
    }
}

// ---------------- + virtual node + softmax (in-place on d_out) ----------------
__global__ void k_softmax(float* __restrict__ Z, const float* __restrict__ r2,
                          const int* __restrict__ batch, int N){
    int r = blockIdx.x*8 + (threadIdx.x>>5);
    int c = threadIdx.x & 31;
    if (r >= N) return;
    float z = Z[(size_t)r*32+c] + r2[batch[r]*32 + c];
    float m = z;
    #pragma unroll
    for (int off=16; off>=1; off>>=1) m = fmaxf(m, __shfl_xor(m, off));
    float e = expf(z - m);
    float s = e;
    #pragma unroll
    for (int off=16; off>=1; off>>=1) s += __shfl_xor(s, off);
    Z[(size_t)r*32+c] = e / s;
}

extern "C" void kernel_launch(void* const* d_in, const int* in_sizes, int n_in,
                              void* d_out, int out_size, void* d_ws, size_t ws_size,
                              hipStream_t stream){
    const float* X   = (const float*)d_in[0];
    const float* W1  = (const float*)d_in[1];
    const float* b1  = (const float*)d_in[2];
    const float* W2  = (const float*)d_in[3];
    const float* b2  = (const float*)d_in[4];
    const float* mW1 = (const float*)d_in[5];
    const float* mb1 = (const float*)d_in[6];
    const float* mW2 = (const float*)d_in[7];
    const float* mb2 = (const float*)d_in[8];
    const int*   ei  = (const int*)d_in[9];
    const int*   batch = (const int*)d_in[10];
    int N = in_sizes[0] / 128;
    int E = in_sizes[9] / 2;
    const int* src = ei;
    const int* dst = ei + E;
    float* Zout = (float*)d_out;

    char* wsp = (char*)d_ws;
    size_t off = 0;
    auto alloc = [&](size_t bytes)->char*{
        char* p = wsp + off; off += (bytes + 255) & ~(size_t)255; return p;
    };
    // zero zone
    int*   bcnt  = (int*)  alloc((size_t)MAXNB*4);
    int*   bfill = (int*)  alloc((size_t)MAXNB*4);
    float* msum  = (float*)alloc((size_t)GNUM*128*4);
    float* msum2 = (float*)alloc((size_t)GNUM*32*4);
    size_t zero_bytes = off;
    // rest
    int*   bbase = (int*)  alloc((size_t)(MAXNB+1)*4);
    int*   rs    = (int*)  alloc((size_t)(N+1)*4);
    int*   gstart= (int*)  alloc((GNUM+1)*4);
    unsigned* ebuf = (unsigned*)alloc((size_t)E*4);
    int*   csr   = (int*)  alloc((size_t)E*4);
    float* dinvp = (float*)alloc((size_t)N*4);
    __half* yh   = (__half*)alloc((size_t)(N+1)*128*2);   // +1: zero row
    __half* h    = (__half*)alloc((size_t)N*128*2);
    __half* y2h  = (__half*)alloc((size_t)(N+1)*32*2);    // +1: zero row
    float* r1buf = (float*)alloc((size_t)GNUM*128*4);
    float* r2buf = (float*)alloc((size_t)GNUM*32*4);
    (void)ws_size; (void)n_in; (void)out_size;

    hipMemsetAsync(d_ws, 0, zero_bytes, stream);

    int NB = (N + 127) >> 7;            // 391
    int EB = (E + CHUNK-1) / CHUNK;     // 391

    k_hist         <<<EB, 256, 0, stream>>>(dst, E, NB, bcnt);
    k_scan1b       <<<1, 256, 0, stream>>>(bcnt, bbase, NB, E, batch, N, gstart);
    k_scatter      <<<EB, 256, 0, stream>>>(src, dst, E, NB, bbase, bfill, ebuf);
    k_bucket_finish<<<NB, 256, 0, stream>>>(ebuf, bbase, rs, csr, dinvp, N, E);

    k_gemm1 <<<(N+31)/32, 256, 0, stream>>>(X, W1, dinvp, yh, N);
    k_agg1  <<<(N+3)/4, 256, 0, stream>>>(yh, dinvp, b1, rs, csr, h, N);

    k_mpoolh<<<dim3(GNUM,8), 64, 0, stream>>>(h, gstart, msum);
    k_mlp1  <<<GNUM, 128, 0, stream>>>(msum, gstart, mW1, mb1, r1buf);

    k_gemm2 <<<(N+63)/64, 256, 0, stream>>>(h, r1buf, batch, W2, dinvp, y2h, N);
    k_agg2h <<<(N+3)/4, 256, 0, stream>>>(y2h, dinvp, b2, rs, csr, Zout, N);

    k_mpool <<<dim3(GNUM,8), 64, 0, stream>>>(Zout, gstart, msum2, 32);
    k_mlp2  <<<GNUM, 64, 0, stream>>>(msum2, gstart, mW2, mb2, r2buf);
    k_softmax<<<(N+7)/8, 256, 0, stream>>>(Zout, r2buf, batch, N);
}

// Round 8
// 241.335 us; speedup vs baseline: 2.1759x; 1.0762x over previous
//
#include <hip/hip_runtime.h>
#include <hip/hip_bf16.h>
#include <hip/hip_fp16.h>

#define DEV_INLINE __device__ __forceinline__

static DEV_INLINE float4 ld4(const float* p){ return *reinterpret_cast<const float4*>(p); }

#define GNUM 64
#define CHUNK 4096
#define MAXNB 1024   // bucket = dst>>7; N <= 65536 (u16 packing)

typedef _Float16 half8 __attribute__((ext_vector_type(8)));
typedef float floatx4 __attribute__((ext_vector_type(4)));

// ======================= bucketed edge build =======================
__global__ __launch_bounds__(256) void k_hist(const int* __restrict__ dst, int E, int NB,
                                              int* __restrict__ bcnt){
    __shared__ int cnt[MAXNB];
    int t = threadIdx.x; int base0 = blockIdx.x*CHUNK;
    for (int i=t;i<NB;i+=256) cnt[i]=0;
    __syncthreads();
    int tot = E - base0; if (tot > CHUNK) tot = CHUNK;
    #pragma unroll
    for (int k=0;k<16;k++){
        int o = t + k*256;
        if (o < tot) atomicAdd(&cnt[dst[base0+o]>>7], 1);
    }
    __syncthreads();
    for (int i=t;i<NB;i+=256) if (cnt[i]) atomicAdd(&bcnt[i], cnt[i]);
}

// one-block exclusive scan (M<=1024) + fused graph-boundary binary search
__global__ void k_scan1b(const int* __restrict__ in, int* __restrict__ out, int M, int total,
                         const int* __restrict__ batch, int N, int* __restrict__ gstart){
    __shared__ int ws[4];
    int t = threadIdx.x;
    int i0 = t*4;
    int c0=(i0+0<M)?in[i0+0]:0, c1=(i0+1<M)?in[i0+1]:0;
    int c2=(i0+2<M)?in[i0+2]:0, c3=(i0+3<M)?in[i0+3]:0;
    int tsum=c0+c1+c2+c3;
    int lane=t&63, w=t>>6;
    int x=tsum;
    for (int off=1;off<64;off<<=1){ int yv=__shfl_up(x,off); if (lane>=off) x+=yv; }
    if (lane==63) ws[w]=x;
    __syncthreads();
    if (t==0){ int a=0; for (int i=0;i<4;i++){ int tmp=ws[i]; ws[i]=a; a+=tmp; } }
    __syncthreads();
    int ex = x - tsum + ws[w];
    if (i0+0<M) out[i0+0]=ex; ex+=c0;
    if (i0+1<M) out[i0+1]=ex; ex+=c1;
    if (i0+2<M) out[i0+2]=ex; ex+=c2;
    if (i0+3<M) out[i0+3]=ex;
    if (t==0 && total>=0) out[M]=total;
    if (t <= GNUM){
        int lo = 0, hi = N;
        while (lo < hi){ int mid = (lo+hi)>>1; if (batch[mid] < t) lo = mid+1; else hi = mid; }
        gstart[t] = lo;
    }
}

__global__ __launch_bounds__(256) void k_scatter(const int* __restrict__ src, const int* __restrict__ dst,
                                                 int E, int NB, const int* __restrict__ bbase,
                                                 int* __restrict__ bfill, unsigned* __restrict__ ebuf){
    __shared__ int cnt[MAXNB];
    __shared__ int pfx[MAXNB];
    __shared__ int gbase[MAXNB];
    __shared__ unsigned stage[CHUNK];
    __shared__ int ws[4];
    int t = threadIdx.x; int base0 = blockIdx.x*CHUNK;
    int tot = E - base0; if (tot > CHUNK) tot = CHUNK;
    for (int i=t;i<NB;i+=256) cnt[i]=0;
    __syncthreads();
    unsigned v[16]; int rk[16];
    #pragma unroll
    for (int k=0;k<16;k++){
        int o = t + k*256;
        if (o < tot){
            int e = base0 + o;
            int s = src[e], d = dst[e];
            v[k] = (unsigned)s | ((unsigned)d<<16);
            rk[k] = atomicAdd(&cnt[d>>7], 1);
        } else { v[k]=0u; rk[k]=-1; }
    }
    __syncthreads();
    int i0 = t*4;
    int c0=(i0+0<NB)?cnt[i0+0]:0, c1=(i0+1<NB)?cnt[i0+1]:0;
    int c2=(i0+2<NB)?cnt[i0+2]:0, c3=(i0+3<NB)?cnt[i0+3]:0;
    int tsum=c0+c1+c2+c3;
    int lane=t&63, w=t>>6;
    int x=tsum;
    for (int off=1;off<64;off<<=1){ int yv=__shfl_up(x,off); if (lane>=off) x+=yv; }
    if (lane==63) ws[w]=x;
    __syncthreads();
    if (t==0){ int a=0; for (int i=0;i<4;i++){ int tmp=ws[i]; ws[i]=a; a+=tmp; } }
    __syncthreads();
    int ex = x - tsum + ws[w];
    if (i0+0<NB) pfx[i0+0]=ex; ex+=c0;
    if (i0+1<NB) pfx[i0+1]=ex; ex+=c1;
    if (i0+2<NB) pfx[i0+2]=ex; ex+=c2;
    if (i0+3<NB) pfx[i0+3]=ex;
    __syncthreads();
    for (int i=t;i<NB;i+=256){
        int c = cnt[i];
        gbase[i] = c ? (bbase[i] + atomicAdd(&bfill[i], c)) : 0;
    }
    __syncthreads();
    #pragma unroll
    for (int k=0;k<16;k++) if (rk[k]>=0){ int b = (int)(v[k]>>23); stage[pfx[b]+rk[k]] = v[k]; }
    __syncthreads();
    for (int j=t;j<tot;j+=256){
        unsigned u = stage[j];
        int b = (int)(u>>23);
        ebuf[gbase[b] + (j - pfx[b])] = u;
    }
}

// fused: per-bucket degree count -> in-LDS prefix -> rs + dinv -> CSR (u16) fill
__global__ __launch_bounds__(256) void k_bucket_finish(const unsigned* __restrict__ ebuf,
                                                       const int* __restrict__ bbase,
                                                       int* __restrict__ rs, unsigned short* __restrict__ csr,
                                                       float* __restrict__ dinv, int N, int E){
    __shared__ int c2[128];
    __shared__ int rsl[128];
    __shared__ int ws[4];
    int b = blockIdx.x, t = threadIdx.x;
    if (t < 128) c2[t] = 0;
    __syncthreads();
    int s0 = bbase[b], s1 = bbase[b+1];
    for (int j = s0+t; j < s1; j += 256)
        atomicAdd(&c2[(ebuf[j]>>16)&127], 1);
    __syncthreads();
    int v = (t < 128) ? c2[t] : 0;
    int lane = t & 63, w = t >> 6;
    int x = v;
    for (int off=1; off<64; off<<=1){
        int yv = __shfl_up(x, off);
        if (lane >= off) x += yv;
    }
    if (lane == 63) ws[w] = x;
    __syncthreads();
    if (t < 128){
        int ex = x - v + ((w == 1) ? ws[0] : 0);
        rsl[t] = s0 + ex;
        int node = (b<<7) + t;
        if (node < N){
            rs[node] = s0 + ex;
            dinv[node] = rsqrtf((float)(v + 1));
        }
    }
    if (b == (int)gridDim.x - 1 && t == 0) rs[N] = E;
    __syncthreads();
    if (t < 128) c2[t] = 0;
    __syncthreads();
    for (int j = s0+t; j < s1; j += 256){
        unsigned u = ebuf[j];
        int ld = (u>>16)&127;
        int p = atomicAdd(&c2[ld], 1);
        csr[rsl[ld]+p] = (unsigned short)(u & 0xffffu);
    }
}

// ---------------- k_prep: W1 (fp32 [k][c]) -> W1T (fp16 [c][136-padded k]) ----------------
__global__ void k_prep(const float* __restrict__ W1, __half* __restrict__ w1t){
    int f = blockIdx.x*256 + threadIdx.x;   // 0..16383
    int c = f >> 7, k = f & 127;
    w1t[c*136 + k] = __float2half(W1[k*128 + c]);
}

// ---------------- GEMM1 (MFMA fp16): y = (X @ W1) * dinv[row], fp16 out ----------------
// A = W1T frag from LDS (row = out-col), B = X rows cvt fp16 (col = out-row).
// D lane layout: col=lane&15 (out row), row=(lane>>4)*4+j (out col) -> uint2 store.
__global__ __launch_bounds__(256) void k_gemm1(const float* __restrict__ X, const __half* __restrict__ w1t,
                                               const float* __restrict__ dinv, __half* __restrict__ yh, int N){
    __shared__ __half Wl[128*136];
    int t = threadIdx.x;
    if (blockIdx.x==0 && t < 32)
        reinterpret_cast<uint2*>(yh + (size_t)N*128)[t] = make_uint2(0u,0u);
    {
        const uint4* g = (const uint4*)w1t;
        uint4* l = (uint4*)Wl;
        for (int i = t; i < 2176; i += 256) l[i] = g[i];   // 128*136*2B / 16
    }
    __syncthreads();
    int wv = t>>6, lane = t&63;
    int r0 = blockIdx.x*64 + wv*16;
    if (r0 >= N) return;
    int lr = lane & 15, lg = lane >> 4;
    int r = r0 + lr;
    bool rok = r < N;
    const float* xrow = X + (size_t)(rok ? r : 0)*128;
    floatx4 acc[8];
    #pragma unroll
    for (int i=0;i<8;i++) acc[i] = (floatx4){0.f,0.f,0.f,0.f};
    #pragma unroll
    for (int ks=0; ks<4; ks++){
        int k0 = ks*32 + lg*8;
        float4 xa = ld4(xrow + k0);
        float4 xb = ld4(xrow + k0 + 4);
        half8 bfrag;
        bfrag[0]=(_Float16)xa.x; bfrag[1]=(_Float16)xa.y; bfrag[2]=(_Float16)xa.z; bfrag[3]=(_Float16)xa.w;
        bfrag[4]=(_Float16)xb.x; bfrag[5]=(_Float16)xb.y; bfrag[6]=(_Float16)xb.z; bfrag[7]=(_Float16)xb.w;
        #pragma unroll
        for (int ct=0; ct<8; ct++){
            half8 afrag = *reinterpret_cast<const half8*>(&Wl[(ct*16 + lr)*136 + k0]);
            acc[ct] = __builtin_amdgcn_mfma_f32_16x16x32_f16(afrag, bfrag, acc[ct], 0, 0, 0);
        }
    }
    if (rok){
        float dv = dinv[r];
        #pragma unroll
        for (int ct=0; ct<8; ct++){
            __half2 p0 = __floats2half2_rn(acc[ct][0]*dv, acc[ct][1]*dv);
            __half2 p1 = __floats2half2_rn(acc[ct][2]*dv, acc[ct][3]*dv);
            uint2 stv; stv.x = *(unsigned*)&p0; stv.y = *(unsigned*)&p1;
            *reinterpret_cast<uint2*>(&yh[(size_t)r*128 + ct*16 + lg*4]) = stv;
        }
    }
}

// ---------------- layer-1 aggregation: quarter-wave 16B gathers, zero-row, fp16 accum ----------------
__global__ void k_agg1(const __half* __restrict__ yh, const float* __restrict__ dinv,
                       const float* __restrict__ b1, const int* __restrict__ rs,
                       const unsigned short* __restrict__ csr, __half* __restrict__ h, int N){
    int wid = (int)((blockIdx.x * blockDim.x + threadIdx.x) >> 6);
    if (wid >= N) return;
    int lane = threadIdx.x & 63;
    int q = lane >> 4, ql = lane & 15;
    int beg = rs[wid], end = rs[wid+1];
    int len = end - beg;
    int qlen = (len + 3) >> 2;
    int qbeg = beg + q*qlen;
    int qend = qbeg + qlen; if (qend > end) qend = end;
    int mylen = qend - qbeg; if (mylen < 0) mylen = 0;
    const uint4* base = reinterpret_cast<const uint4*>(yh) + ql;   // 16B slice of 256B row
    float f0=0.f,f1=0.f,f2=0.f,f3=0.f,f4=0.f,f5=0.f,f6=0.f,f7=0.f;
    int iters = (qlen + 15) >> 4;
    for (int c=0;c<iters;c++){
        int o = c*16 + ql;
        int idx = (o < mylen) ? (int)csr[qbeg + o] : N;   // N = zero row
        int tmax = qlen - c*16; if (tmax > 16) tmax = 16;
        int nch = (tmax + 3) >> 2;
        __half2 a0 = __float2half2_rn(0.f), a1 = a0, a2 = a0, a3 = a0;
        for (int ch=0; ch<nch; ++ch){
            int tb = (q<<4) + ch*4;
            int s0 = __shfl(idx, tb+0);
            int s1 = __shfl(idx, tb+1);
            int s2 = __shfl(idx, tb+2);
            int s3 = __shfl(idx, tb+3);
            uint4 u0 = base[(size_t)s0*16];
            uint4 u1 = base[(size_t)s1*16];
            uint4 u2 = base[(size_t)s2*16];
            uint4 u3 = base[(size_t)s3*16];
            a0 = __hadd2(a0, *(__half2*)&u0.x); a1 = __hadd2(a1, *(__half2*)&u0.y);
            a2 = __hadd2(a2, *(__half2*)&u0.z); a3 = __hadd2(a3, *(__half2*)&u0.w);
            a0 = __hadd2(a0, *(__half2*)&u1.x); a1 = __hadd2(a1, *(__half2*)&u1.y);
            a2 = __hadd2(a2, *(__half2*)&u1.z); a3 = __hadd2(a3, *(__half2*)&u1.w);
            a0 = __hadd2(a0, *(__half2*)&u2.x); a1 = __hadd2(a1, *(__half2*)&u2.y);
            a2 = __hadd2(a2, *(__half2*)&u2.z); a3 = __hadd2(a3, *(__half2*)&u2.w);
            a0 = __hadd2(a0, *(__half2*)&u3.x); a1 = __hadd2(a1, *(__half2*)&u3.y);
            a2 = __hadd2(a2, *(__half2*)&u3.z); a3 = __hadd2(a3, *(__half2*)&u3.w);
        }
        float2 t0 = __half22float2(a0); f0 += t0.x; f1 += t0.y;
        float2 t1 = __half22float2(a1); f2 += t1.x; f3 += t1.y;
        float2 t2 = __half22float2(a2); f4 += t2.x; f5 += t2.y;
        float2 t3 = __half22float2(a3); f6 += t3.x; f7 += t3.y;
    }
    f0 += __shfl_xor(f0,16); f1 += __shfl_xor(f1,16); f2 += __shfl_xor(f2,16); f3 += __shfl_xor(f3,16);
    f4 += __shfl_xor(f4,16); f5 += __shfl_xor(f5,16); f6 += __shfl_xor(f6,16); f7 += __shfl_xor(f7,16);
    f0 += __shfl_xor(f0,32); f1 += __shfl_xor(f1,32); f2 += __shfl_xor(f2,32); f3 += __shfl_xor(f3,32);
    f4 += __shfl_xor(f4,32); f5 += __shfl_xor(f5,32); f6 += __shfl_xor(f6,32); f7 += __shfl_xor(f7,32);
    if (q == 0){
        uint4 su = base[(size_t)wid*16];   // self loop
        float2 s0 = __half22float2(*(__half2*)&su.x); f0 += s0.x; f1 += s0.y;
        float2 s1 = __half22float2(*(__half2*)&su.y); f2 += s1.x; f3 += s1.y;
        float2 s2 = __half22float2(*(__half2*)&su.z); f4 += s2.x; f5 += s2.y;
        float2 s3 = __half22float2(*(__half2*)&su.w); f6 += s3.x; f7 += s3.y;
        float dv = dinv[wid];
        float4 ba = ld4(&b1[ql*8]), bb = ld4(&b1[ql*8+4]);
        float o0 = dv*f0+ba.x, o1 = dv*f1+ba.y, o2 = dv*f2+ba.z, o3 = dv*f3+ba.w;
        float o4 = dv*f4+bb.x, o5 = dv*f5+bb.y, o6 = dv*f6+bb.z, o7 = dv*f7+bb.w;
        o0 = o0>0.f?o0:expm1f(o0); o1 = o1>0.f?o1:expm1f(o1);
        o2 = o2>0.f?o2:expm1f(o2); o3 = o3>0.f?o3:expm1f(o3);
        o4 = o4>0.f?o4:expm1f(o4); o5 = o5>0.f?o5:expm1f(o5);
        o6 = o6>0.f?o6:expm1f(o6); o7 = o7>0.f?o7:expm1f(o7);
        __half2 p0 = __floats2half2_rn(o0,o1), p1 = __floats2half2_rn(o2,o3);
        __half2 p2 = __floats2half2_rn(o4,o5), p3 = __floats2half2_rn(o6,o7);
        uint4 stv; stv.x=*(unsigned*)&p0; stv.y=*(unsigned*)&p1; stv.z=*(unsigned*)&p2; stv.w=*(unsigned*)&p3;
        *reinterpret_cast<uint4*>(&h[(size_t)wid*128 + ql*8]) = stv;
    }
}

// ---------------- mean-pool partial sums (streaming, few atomics) ----------------
__global__ void k_mpoolh(const __half* __restrict__ hsrc, const int* __restrict__ gstart,
                         float* __restrict__ msum){
    int g = blockIdx.x, part = blockIdx.y, P = gridDim.y;
    int c = threadIdx.x;   // 64 threads, half2 cols
    int s0 = gstart[g], s1 = gstart[g+1];
    int len = s1 - s0;
    int per = (len + P - 1) / P;
    int rbeg = s0 + part*per, rend = rbeg + per; if (rend > s1) rend = s1;
    float sx = 0.f, sy = 0.f;
    const __half2* h2 = (const __half2*)hsrc;
    for (int r = rbeg; r < rend; ++r){
        float2 f = __half22float2(h2[(size_t)r*64 + c]);
        sx += f.x; sy += f.y;
    }
    if (rend > rbeg){
        atomicAdd(&msum[g*128 + 2*c], sx);
        atomicAdd(&msum[g*128 + 2*c+1], sy);
    }
}

__global__ void k_mpool(const float* __restrict__ srcm, const int* __restrict__ gstart,
                        float* __restrict__ msum, int C){
    int g = blockIdx.x, part = blockIdx.y, P = gridDim.y;
    int c = threadIdx.x;
    if (c >= C) return;
    int s0 = gstart[g], s1 = gstart[g+1];
    int len = s1 - s0;
    int per = (len + P - 1) / P;
    int rbeg = s0 + part*per, rend = rbeg + per; if (rend > s1) rend = s1;
    float sum = 0.f;
    for (int r = rbeg; r < rend; ++r) sum += srcm[(size_t)r*C + c];
    if (rend > rbeg) atomicAdd(&msum[g*C + c], sum);
}

__global__ void k_mlp1(const float* __restrict__ msum, const int* __restrict__ gstart,
                       const float* __restrict__ mW1, const float* __restrict__ mb1,
                       float* __restrict__ r1){
    int g = blockIdx.x, c = threadIdx.x;   // 128 threads
    int cnt = gstart[g+1] - gstart[g];
    float inv = 1.f / (float)(cnt > 1 ? cnt : 1);
    float acc = mb1[c];
    for (int k=0;k<128;k++) acc = fmaf(msum[g*128+k]*inv, mW1[k*128+c], acc);
    r1[g*128+c] = fmaxf(acc, 0.f);
}

__global__ void k_mlp2(const float* __restrict__ msum2, const int* __restrict__ gstart,
                       const float* __restrict__ mW2, const float* __restrict__ mb2,
                       float* __restrict__ r2){
    int g = blockIdx.x, c = threadIdx.x;
    if (c >= 32) return;
    int cnt = gstart[g+1] - gstart[g];
    float inv = 1.f / (float)(cnt > 1 ? cnt : 1);
    float acc = mb2[c];
    for (int k=0;k<32;k++) acc = fmaf(msum2[g*32+k]*inv, mW2[k*32+c], acc);
    r2[g*32+c] = fmaxf(acc, 0.f);
}

// ---------------- GEMM2: y2 = ((h + r1[batch]) @ W2) * dinv, fp16 in/out ----------------
__global__ __launch_bounds__(256) void k_gemm2(const __half* __restrict__ h, const float* __restrict__ vn,
                                               const int* __restrict__ batch, const float* __restrict__ W2,
                                               const float* __restrict__ dinv, __half* __restrict__ y2, int N){
    __shared__ float W2s[128*32];
    int t = threadIdx.x;
    if (blockIdx.x==0 && t < 8)
        reinterpret_cast<uint2*>(y2 + (size_t)N*32)[t] = make_uint2(0u,0u);
    {
        float4* Wl = (float4*)W2s;
        const float4* Wg = (const float4*)W2;
        #pragma unroll
        for (int i=0;i<4;i++) Wl[t + i*256] = Wg[t + i*256];
    }
    __syncthreads();
    int row0 = blockIdx.x*64;
    int tc = t & 7, trg = t >> 3;
    int ra = row0 + 2*trg, rb = ra + 1;
    bool oka = ra < N, okb = rb < N;
    const __half* hpa = h + (size_t)(oka ? ra : 0)*128;
    const __half* hpb = h + (size_t)(okb ? rb : 0)*128;
    const float* vpa = vn + (size_t)(oka ? batch[ra] : 0)*128;
    const float* vpb = vn + (size_t)(okb ? batch[rb] : 0)*128;
    float4 acca={0,0,0,0}, accb={0,0,0,0};
    for (int k=0;k<128;k+=4){
        float4 w0 = ld4(&W2s[(k+0)*32 + tc*4]);
        float4 w1 = ld4(&W2s[(k+1)*32 + tc*4]);
        float4 w2 = ld4(&W2s[(k+2)*32 + tc*4]);
        float4 w3 = ld4(&W2s[(k+3)*32 + tc*4]);
        {
            uint2 u = *reinterpret_cast<const uint2*>(&hpa[k]);
            float2 f0 = __half22float2(*(__half2*)&u.x), f1 = __half22float2(*(__half2*)&u.y);
            float4 bb = ld4(vpa + k);
            float ax=f0.x+bb.x, ay=f0.y+bb.y, az=f1.x+bb.z, aw=f1.y+bb.w;
            acca.x += ax*w0.x + ay*w1.x + az*w2.x + aw*w3.x;
            acca.y += ax*w0.y + ay*w1.y + az*w2.y + aw*w3.y;
            acca.z += ax*w0.z + ay*w1.z + az*w2.z + aw*w3.z;
            acca.w += ax*w0.w + ay*w1.w + az*w2.w + aw*w3.w;
        }
        {
            uint2 u = *reinterpret_cast<const uint2*>(&hpb[k]);
            float2 f0 = __half22float2(*(__half2*)&u.x), f1 = __half22float2(*(__half2*)&u.y);
            float4 bb = ld4(vpb + k);
            float ax=f0.x+bb.x, ay=f0.y+bb.y, az=f1.x+bb.z, aw=f1.y+bb.w;
            accb.x += ax*w0.x + ay*w1.x + az*w2.x + aw*w3.x;
            accb.y += ax*w0.y + ay*w1.y + az*w2.y + aw*w3.y;
            accb.z += ax*w0.z + ay*w1.z + az*w2.z + aw*w3.z;
            accb.w += ax*w0.w + ay*w1.w + az*w2.w + aw*w3.w;
        }
    }
    if (oka){
        float dv = dinv[ra];
        __half2 p0 = __floats2half2_rn(acca.x*dv, acca.y*dv);
        __half2 p1 = __floats2half2_rn(acca.z*dv, acca.w*dv);
        uint2 stv; stv.x = *(unsigned*)&p0; stv.y = *(unsigned*)&p1;
        *reinterpret_cast<uint2*>(&y2[(size_t)ra*32 + tc*4]) = stv;
    }
    if (okb){
        float dv = dinv[rb];
        __half2 p0 = __floats2half2_rn(accb.x*dv, accb.y*dv);
        __half2 p1 = __floats2half2_rn(accb.z*dv, accb.w*dv);
        uint2 stv; stv.x = *(unsigned*)&p0; stv.y = *(unsigned*)&p1;
        *reinterpret_cast<uint2*>(&y2[(size_t)rb*32 + tc*4]) = stv;
    }
}

// ---------------- layer-2 aggregation: octet-wave 8B gathers, zero-row, fp16 accum ----------------
__global__ void k_agg2h(const __half* __restrict__ y2, const float* __restrict__ dinv,
                        const float* __restrict__ b2, const int* __restrict__ rs,
                        const unsigned short* __restrict__ csr, float* __restrict__ Z, int N){
    int wid = (int)((blockIdx.x*blockDim.x + threadIdx.x) >> 6);
    if (wid >= N) return;
    int lane = threadIdx.x & 63;
    int o8 = lane >> 3, ol = lane & 7;
    int beg = rs[wid], end = rs[wid+1], len = end-beg;
    int olen = (len + 7) >> 3;
    int obeg = beg + o8*olen;
    int oend = obeg + olen; if (oend > end) oend = end;
    int mylen = oend - obeg; if (mylen < 0) mylen = 0;
    const uint2* base = reinterpret_cast<const uint2*>(y2) + ol;   // 8B slice of 64B row
    float f0=0.f, f1=0.f, f2=0.f, f3=0.f;
    int iters = (olen + 7) >> 3;
    for (int c=0;c<iters;c++){
        int o = c*8 + ol;
        int idx = (o < mylen) ? (int)csr[obeg + o] : N;
        int tmax = olen - c*8; if (tmax > 8) tmax = 8;
        int nch = (tmax + 3) >> 2;
        __half2 a0 = __float2half2_rn(0.f), a1 = a0;
        for (int ch=0; ch<nch; ++ch){
            int tb = (o8<<3) + ch*4;
            int s0 = __shfl(idx, tb+0);
            int s1 = __shfl(idx, tb+1);
            int s2 = __shfl(idx, tb+2);
            int s3 = __shfl(idx, tb+3);
            uint2 u0 = base[(size_t)s0*8];
            uint2 u1 = base[(size_t)s1*8];
            uint2 u2 = base[(size_t)s2*8];
            uint2 u3 = base[(size_t)s3*8];
            a0 = __hadd2(a0, *(__half2*)&u0.x); a1 = __hadd2(a1, *(__half2*)&u0.y);
            a0 = __hadd2(a0, *(__half2*)&u1.x); a1 = __hadd2(a1, *(__half2*)&u1.y);
            a0 = __hadd2(a0, *(__half2*)&u2.x); a1 = __hadd2(a1, *(__half2*)&u2.y);
            a0 = __hadd2(a0, *(__half2*)&u3.x); a1 = __hadd2(a1, *(__half2*)&u3.y);
        }
        float2 t0 = __half22float2(a0); f0 += t0.x; f1 += t0.y;
        float2 t1 = __half22float2(a1); f2 += t1.x; f3 += t1.y;
    }
    f0 += __shfl_xor(f0,8);  f1 += __shfl_xor(f1,8);  f2 += __shfl_xor(f2,8);  f3 += __shfl_xor(f3,8);
    f0 += __shfl_xor(f0,16); f1 += __shfl_xor(f1,16); f2 += __shfl_xor(f2,16); f3 += __shfl_xor(f3,16);
    f0 += __shfl_xor(f0,32); f1 += __shfl_xor(f1,32); f2 += __shfl_xor(f2,32); f3 += __shfl_xor(f3,32);
    if (o8 == 0){
        uint2 su = base[(size_t)wid*8];   // self loop
        float2 s0 = __half22float2(*(__half2*)&su.x); f0 += s0.x; f1 += s0.y;
        float2 s1 = __half22float2(*(__half2*)&su.y); f2 += s1.x; f3 += s1.y;
        float dv = dinv[wid];
        float4 bb = ld4(&b2[ol*4]);
        float4 outv;
        outv.x = dv*f0 + bb.x; outv.y = dv*f1 + bb.y;
        outv.z = dv*f2 + bb.z; outv.w = dv*f3 + bb.w;
        *reinterpret_cast<float4*>(&Z[(size_t)wid*32 + ol*4]) = outv;
    }
}

// ---------------- + virtual node + softmax (in-place on d_out) ----------------
__global__ void k_softmax(float* __restrict__ Z, const float* __restrict__ r2,
                          const int* __restrict__ batch, int N){
    int r = blockIdx.x*8 + (threadIdx.x>>5);
    int c = threadIdx.x & 31;
    if (r >= N) return;
    float z = Z[(size_t)r*32+c] + r2[batch[r]*32 + c];
    float m = z;
    #pragma unroll
    for (int off=16; off>=1; off>>=1) m = fmaxf(m, __shfl_xor(m, off));
    float e = expf(z - m);
    float s = e;
    #pragma unroll
    for (int off=16; off>=1; off>>=1) s += __shfl_xor(s, off);
    Z[(size_t)r*32+c] = e / s;
}

extern "C" void kernel_launch(void* const* d_in, const int* in_sizes, int n_in,
                              void* d_out, int out_size, void* d_ws, size_t ws_size,
                              hipStream_t stream){
    const float* X   = (const float*)d_in[0];
    const float* W1  = (const float*)d_in[1];
    const float* b1  = (const float*)d_in[2];
    const float* W2  = (const float*)d_in[3];
    const float* b2  = (const float*)d_in[4];
    const float* mW1 = (const float*)d_in[5];
    const float* mb1 = (const float*)d_in[6];
    const float* mW2 = (const float*)d_in[7];
    const float* mb2 = (const float*)d_in[8];
    const int*   ei  = (const int*)d_in[9];
    const int*   batch = (const int*)d_in[10];
    int N = in_sizes[0] / 128;
    int E = in_sizes[9] / 2;
    const int* src = ei;
    const int* dst = ei + E;
    float* Zout = (float*)d_out;

    char* wsp = (char*)d_ws;
    size_t off = 0;
    auto alloc = [&](size_t bytes)->char*{
        char* p = wsp + off; off += (bytes + 255) & ~(size_t)255; return p;
    };
    // zero zone
    int*   bcnt  = (int*)  alloc((size_t)MAXNB*4);
    int*   bfill = (int*)  alloc((size_t)MAXNB*4);
    float* msum  = (float*)alloc((size_t)GNUM*128*4);
    float* msum2 = (float*)alloc((size_t)GNUM*32*4);
    size_t zero_bytes = off;
    // rest
    int*   bbase = (int*)  alloc((size_t)(MAXNB+1)*4);
    int*   rs    = (int*)  alloc((size_t)(N+1)*4);
    int*   gstart= (int*)  alloc((GNUM+1)*4);
    unsigned* ebuf = (unsigned*)alloc((size_t)E*4);
    unsigned short* csr = (unsigned short*)alloc((size_t)E*2);
    float* dinvp = (float*)alloc((size_t)N*4);
    __half* w1t  = (__half*)alloc((size_t)128*136*2);
    __half* yh   = (__half*)alloc((size_t)(N+1)*128*2);   // +1: zero row
    __half* h    = (__half*)alloc((size_t)N*128*2);
    __half* y2h  = (__half*)alloc((size_t)(N+1)*32*2);    // +1: zero row
    float* r1buf = (float*)alloc((size_t)GNUM*128*4);
    float* r2buf = (float*)alloc((size_t)GNUM*32*4);
    (void)ws_size; (void)n_in; (void)out_size;

    hipMemsetAsync(d_ws, 0, zero_bytes, stream);

    int NB = (N + 127) >> 7;            // 391
    int EB = (E + CHUNK-1) / CHUNK;     // 391

    k_prep         <<<64, 256, 0, stream>>>(W1, w1t);
    k_hist         <<<EB, 256, 0, stream>>>(dst, E, NB, bcnt);
    k_scan1b       <<<1, 256, 0, stream>>>(bcnt, bbase, NB, E, batch, N, gstart);
    k_scatter      <<<EB, 256, 0, stream>>>(src, dst, E, NB, bbase, bfill, ebuf);
    k_bucket_finish<<<NB, 256, 0, stream>>>(ebuf, bbase, rs, csr, dinvp, N, E);

    k_gemm1 <<<(N+63)/64, 256, 0, stream>>>(X, w1t, dinvp, yh, N);
    k_agg1  <<<(N+3)/4, 256, 0, stream>>>(yh, dinvp, b1, rs, csr, h, N);

    k_mpoolh<<<dim3(GNUM,8), 64, 0, stream>>>(h, gstart, msum);
    k_mlp1  <<<GNUM, 128, 0, stream>>>(msum, gstart, mW1, mb1, r1buf);

    k_gemm2 <<<(N+63)/64, 256, 0, stream>>>(h, r1buf, batch, W2, dinvp, y2h, N);
    k_agg2h <<<(N+3)/4, 256, 0, stream>>>(y2h, dinvp, b2, rs, csr, Zout, N);

    k_mpool <<<dim3(GNUM,8), 64, 0, stream>>>(Zout, gstart, msum2, 32);
    k_mlp2  <<<GNUM, 64, 0, stream>>>(msum2, gstart, mW2, mb2, r2buf);
    k_softmax<<<(N+7)/8, 256, 0, stream>>>(Zout, r2buf, batch, N);
}

// Round 9
// 226.968 us; speedup vs baseline: 2.3136x; 1.0633x over previous
//
#include <hip/hip_runtime.h>
#include <hip/hip_bf16.h>
#include <hip/hip_fp16.h>

#define DEV_INLINE __device__ __forceinline__

static DEV_INLINE float4 ld4(const float* p){ return *reinterpret_cast<const float4*>(p); }

#define GNUM 64
#define CHUNK 4096
#define MAXNB 1024   // bucket = dst>>7; N <= 65536 (u16 packing)

typedef _Float16 half8 __attribute__((ext_vector_type(8)));
typedef float floatx4 __attribute__((ext_vector_type(4)));

#define W1T_ELEMS (128*136)   // 17408
#define W2T_ELEMS (32*136)    // 4352

// ======================= bucketed edge build (+ fused weight prep) =======================
__global__ __launch_bounds__(256) void k_hist(const int* __restrict__ dst, int E, int NB,
                                              int* __restrict__ bcnt,
                                              const float* __restrict__ W1, const float* __restrict__ W2,
                                              __half* __restrict__ w1t, __half* __restrict__ w2t, int EB){
    if ((int)blockIdx.x >= EB){
        int f = ((int)blockIdx.x - EB)*256 + threadIdx.x;
        if (f < W1T_ELEMS){
            int c = f/136, k = f - c*136;
            w1t[f] = (k<128) ? __float2half(W1[k*128+c]) : __float2half(0.f);
        } else {
            int f2 = f - W1T_ELEMS;
            if (f2 < W2T_ELEMS){
                int c = f2/136, k = f2 - c*136;
                w2t[f2] = (k<128) ? __float2half(W2[k*32+c]) : __float2half(0.f);
            }
        }
        return;
    }
    __shared__ int cnt[MAXNB];
    int t = threadIdx.x; int base0 = blockIdx.x*CHUNK;
    for (int i=t;i<NB;i+=256) cnt[i]=0;
    __syncthreads();
    int tot = E - base0; if (tot > CHUNK) tot = CHUNK;
    #pragma unroll
    for (int k=0;k<16;k++){
        int o = t + k*256;
        if (o < tot) atomicAdd(&cnt[dst[base0+o]>>7], 1);
    }
    __syncthreads();
    for (int i=t;i<NB;i+=256) if (cnt[i]) atomicAdd(&bcnt[i], cnt[i]);
}

// one-block exclusive scan (M<=1024) + fused graph-boundary binary search
__global__ void k_scan1b(const int* __restrict__ in, int* __restrict__ out, int M, int total,
                         const int* __restrict__ batch, int N, int* __restrict__ gstart){
    __shared__ int ws[4];
    int t = threadIdx.x;
    int i0 = t*4;
    int c0=(i0+0<M)?in[i0+0]:0, c1=(i0+1<M)?in[i0+1]:0;
    int c2=(i0+2<M)?in[i0+2]:0, c3=(i0+3<M)?in[i0+3]:0;
    int tsum=c0+c1+c2+c3;
    int lane=t&63, w=t>>6;
    int x=tsum;
    for (int off=1;off<64;off<<=1){ int yv=__shfl_up(x,off); if (lane>=off) x+=yv; }
    if (lane==63) ws[w]=x;
    __syncthreads();
    if (t==0){ int a=0; for (int i=0;i<4;i++){ int tmp=ws[i]; ws[i]=a; a+=tmp; } }
    __syncthreads();
    int ex = x - tsum + ws[w];
    if (i0+0<M) out[i0+0]=ex; ex+=c0;
    if (i0+1<M) out[i0+1]=ex; ex+=c1;
    if (i0+2<M) out[i0+2]=ex; ex+=c2;
    if (i0+3<M) out[i0+3]=ex;
    if (t==0 && total>=0) out[M]=total;
    if (t <= GNUM){
        int lo = 0, hi = N;
        while (lo < hi){ int mid = (lo+hi)>>1; if (batch[mid] < t) lo = mid+1; else hi = mid; }
        gstart[t] = lo;
    }
}

__global__ __launch_bounds__(256) void k_scatter(const int* __restrict__ src, const int* __restrict__ dst,
                                                 int E, int NB, const int* __restrict__ bbase,
                                                 int* __restrict__ bfill, unsigned* __restrict__ ebuf){
    __shared__ int cnt[MAXNB];
    __shared__ int pfx[MAXNB];
    __shared__ int gbase[MAXNB];
    __shared__ unsigned stage[CHUNK];
    __shared__ int ws[4];
    int t = threadIdx.x; int base0 = blockIdx.x*CHUNK;
    int tot = E - base0; if (tot > CHUNK) tot = CHUNK;
    for (int i=t;i<NB;i+=256) cnt[i]=0;
    __syncthreads();
    unsigned v[16]; int rk[16];
    #pragma unroll
    for (int k=0;k<16;k++){
        int o = t + k*256;
        if (o < tot){
            int e = base0 + o;
            int s = src[e], d = dst[e];
            v[k] = (unsigned)s | ((unsigned)d<<16);
            rk[k] = atomicAdd(&cnt[d>>7], 1);
        } else { v[k]=0u; rk[k]=-1; }
    }
    __syncthreads();
    int i0 = t*4;
    int c0=(i0+0<NB)?cnt[i0+0]:0, c1=(i0+1<NB)?cnt[i0+1]:0;
    int c2=(i0+2<NB)?cnt[i0+2]:0, c3=(i0+3<NB)?cnt[i0+3]:0;
    int tsum=c0+c1+c2+c3;
    int lane=t&63, w=t>>6;
    int x=tsum;
    for (int off=1;off<64;off<<=1){ int yv=__shfl_up(x,off); if (lane>=off) x+=yv; }
    if (lane==63) ws[w]=x;
    __syncthreads();
    if (t==0){ int a=0; for (int i=0;i<4;i++){ int tmp=ws[i]; ws[i]=a; a+=tmp; } }
    __syncthreads();
    int ex = x - tsum + ws[w];
    if (i0+0<NB) pfx[i0+0]=ex; ex+=c0;
    if (i0+1<NB) pfx[i0+1]=ex; ex+=c1;
    if (i0+2<NB) pfx[i0+2]=ex; ex+=c2;
    if (i0+3<NB) pfx[i0+3]=ex;
    __syncthreads();
    for (int i=t;i<NB;i+=256){
        int c = cnt[i];
        gbase[i] = c ? (bbase[i] + atomicAdd(&bfill[i], c)) : 0;
    }
    __syncthreads();
    #pragma unroll
    for (int k=0;k<16;k++) if (rk[k]>=0){ int b = (int)(v[k]>>23); stage[pfx[b]+rk[k]] = v[k]; }
    __syncthreads();
    for (int j=t;j<tot;j+=256){
        unsigned u = stage[j];
        int b = (int)(u>>23);
        ebuf[gbase[b] + (j - pfx[b])] = u;
    }
}

// fused: per-bucket degree count -> in-LDS prefix -> rs + dinv -> CSR (u16) fill
__global__ __launch_bounds__(256) void k_bucket_finish(const unsigned* __restrict__ ebuf,
                                                       const int* __restrict__ bbase,
                                                       int* __restrict__ rs, unsigned short* __restrict__ csr,
                                                       float* __restrict__ dinv, int N, int E){
    __shared__ int c2[128];
    __shared__ int rsl[128];
    __shared__ int ws[4];
    int b = blockIdx.x, t = threadIdx.x;
    if (t < 128) c2[t] = 0;
    __syncthreads();
    int s0 = bbase[b], s1 = bbase[b+1];
    for (int j = s0+t; j < s1; j += 256)
        atomicAdd(&c2[(ebuf[j]>>16)&127], 1);
    __syncthreads();
    int v = (t < 128) ? c2[t] : 0;
    int lane = t & 63, w = t >> 6;
    int x = v;
    for (int off=1; off<64; off<<=1){
        int yv = __shfl_up(x, off);
        if (lane >= off) x += yv;
    }
    if (lane == 63) ws[w] = x;
    __syncthreads();
    if (t < 128){
        int ex = x - v + ((w == 1) ? ws[0] : 0);
        rsl[t] = s0 + ex;
        int node = (b<<7) + t;
        if (node < N){
            rs[node] = s0 + ex;
            dinv[node] = rsqrtf((float)(v + 1));
        }
    }
    if (b == (int)gridDim.x - 1 && t == 0) rs[N] = E;
    __syncthreads();
    if (t < 128) c2[t] = 0;
    __syncthreads();
    for (int j = s0+t; j < s1; j += 256){
        unsigned u = ebuf[j];
        int ld = (u>>16)&127;
        int p = atomicAdd(&c2[ld], 1);
        csr[rsl[ld]+p] = (unsigned short)(u & 0xffffu);
    }
}

// ---------------- GEMM1 (MFMA fp16): y = (X @ W1) * dinv[row], fp16 out ----------------
__global__ __launch_bounds__(256) void k_gemm1(const float* __restrict__ X, const __half* __restrict__ w1t,
                                               const float* __restrict__ dinv, __half* __restrict__ yh, int N){
    __shared__ __half Wl[128*136];
    int t = threadIdx.x;
    if (blockIdx.x==0 && t < 32)
        reinterpret_cast<uint2*>(yh + (size_t)N*128)[t] = make_uint2(0u,0u);
    {
        const uint4* g = (const uint4*)w1t;
        uint4* l = (uint4*)Wl;
        for (int i = t; i < 2176; i += 256) l[i] = g[i];
    }
    __syncthreads();
    int wv = t>>6, lane = t&63;
    int r0 = blockIdx.x*64 + wv*16;
    if (r0 >= N) return;
    int lr = lane & 15, lg = lane >> 4;
    int r = r0 + lr;
    bool rok = r < N;
    const float* xrow = X + (size_t)(rok ? r : 0)*128;
    floatx4 acc[8];
    #pragma unroll
    for (int i=0;i<8;i++) acc[i] = (floatx4){0.f,0.f,0.f,0.f};
    #pragma unroll
    for (int ks=0; ks<4; ks++){
        int k0 = ks*32 + lg*8;
        float4 xa = ld4(xrow + k0);
        float4 xb = ld4(xrow + k0 + 4);
        half8 bfrag;
        bfrag[0]=(_Float16)xa.x; bfrag[1]=(_Float16)xa.y; bfrag[2]=(_Float16)xa.z; bfrag[3]=(_Float16)xa.w;
        bfrag[4]=(_Float16)xb.x; bfrag[5]=(_Float16)xb.y; bfrag[6]=(_Float16)xb.z; bfrag[7]=(_Float16)xb.w;
        #pragma unroll
        for (int ct=0; ct<8; ct++){
            half8 afrag = *reinterpret_cast<const half8*>(&Wl[(ct*16 + lr)*136 + k0]);
            acc[ct] = __builtin_amdgcn_mfma_f32_16x16x32_f16(afrag, bfrag, acc[ct], 0, 0, 0);
        }
    }
    if (rok){
        float dv = dinv[r];
        #pragma unroll
        for (int ct=0; ct<8; ct++){
            __half2 p0 = __floats2half2_rn(acc[ct][0]*dv, acc[ct][1]*dv);
            __half2 p1 = __floats2half2_rn(acc[ct][2]*dv, acc[ct][3]*dv);
            uint2 stv; stv.x = *(unsigned*)&p0; stv.y = *(unsigned*)&p1;
            *reinterpret_cast<uint2*>(&yh[(size_t)r*128 + ct*16 + lg*4]) = stv;
        }
    }
}

// ---------------- layer-1 aggregation: quarter-wave 16B gathers, 32-bit offsets, 8-deep ILP ----------------
__global__ void k_agg1(const __half* __restrict__ yh, const float* __restrict__ dinv,
                       const float* __restrict__ b1, const int* __restrict__ rs,
                       const unsigned short* __restrict__ csr, __half* __restrict__ h, int N){
    int wid = (int)((blockIdx.x * blockDim.x + threadIdx.x) >> 6);
    if (wid >= N) return;
    int lane = threadIdx.x & 63;
    int q = lane >> 4, ql = lane & 15;
    int beg = rs[wid], end = rs[wid+1];
    int len = end - beg;
    int qlen = (len + 3) >> 2;
    int qbeg = beg + q*qlen;
    int qend = qbeg + qlen; if (qend > end) qend = end;
    int mylen = qend - qbeg; if (mylen < 0) mylen = 0;
    const char* yb = (const char*)yh;
    unsigned lofs = (unsigned)ql * 16u;
    float f0=0.f,f1=0.f,f2=0.f,f3=0.f,f4=0.f,f5=0.f,f6=0.f,f7=0.f;
    int iters = (qlen + 15) >> 4;
    for (int c=0;c<iters;c++){
        int o = c*16 + ql;
        int idx = (o < mylen) ? (int)csr[qbeg + o] : N;   // N = zero row
        int tmax = qlen - c*16; if (tmax > 16) tmax = 16;
        int nch = (tmax + 7) >> 3;
        __half2 a0 = __float2half2_rn(0.f), a1 = a0, a2 = a0, a3 = a0;
        for (int ch=0; ch<nch; ++ch){
            int tb = (q<<4) + ch*8;
            int s0 = __shfl(idx, tb+0);
            int s1 = __shfl(idx, tb+1);
            int s2 = __shfl(idx, tb+2);
            int s3 = __shfl(idx, tb+3);
            int s4 = __shfl(idx, tb+4);
            int s5 = __shfl(idx, tb+5);
            int s6 = __shfl(idx, tb+6);
            int s7 = __shfl(idx, tb+7);
            uint4 u0 = *(const uint4*)(yb + (((unsigned)s0<<8) + lofs));
            uint4 u1 = *(const uint4*)(yb + (((unsigned)s1<<8) + lofs));
            uint4 u2 = *(const uint4*)(yb + (((unsigned)s2<<8) + lofs));
            uint4 u3 = *(const uint4*)(yb + (((unsigned)s3<<8) + lofs));
            uint4 u4 = *(const uint4*)(yb + (((unsigned)s4<<8) + lofs));
            uint4 u5 = *(const uint4*)(yb + (((unsigned)s5<<8) + lofs));
            uint4 u6 = *(const uint4*)(yb + (((unsigned)s6<<8) + lofs));
            uint4 u7 = *(const uint4*)(yb + (((unsigned)s7<<8) + lofs));
            a0 = __hadd2(a0, *(__half2*)&u0.x); a1 = __hadd2(a1, *(__half2*)&u0.y);
            a2 = __hadd2(a2, *(__half2*)&u0.z); a3 = __hadd2(a3, *(__half2*)&u0.w);
            a0 = __hadd2(a0, *(__half2*)&u1.x); a1 = __hadd2(a1, *(__half2*)&u1.y);
            a2 = __hadd2(a2, *(__half2*)&u1.z); a3 = __hadd2(a3, *(__half2*)&u1.w);
            a0 = __hadd2(a0, *(__half2*)&u2.x); a1 = __hadd2(a1, *(__half2*)&u2.y);
            a2 = __hadd2(a2, *(__half2*)&u2.z); a3 = __hadd2(a3, *(__half2*)&u2.w);
            a0 = __hadd2(a0, *(__half2*)&u3.x); a1 = __hadd2(a1, *(__half2*)&u3.y);
            a2 = __hadd2(a2, *(__half2*)&u3.z); a3 = __hadd2(a3, *(__half2*)&u3.w);
            a0 = __hadd2(a0, *(__half2*)&u4.x); a1 = __hadd2(a1, *(__half2*)&u4.y);
            a2 = __hadd2(a2, *(__half2*)&u4.z); a3 = __hadd2(a3, *(__half2*)&u4.w);
            a0 = __hadd2(a0, *(__half2*)&u5.x); a1 = __hadd2(a1, *(__half2*)&u5.y);
            a2 = __hadd2(a2, *(__half2*)&u5.z); a3 = __hadd2(a3, *(__half2*)&u5.w);
            a0 = __hadd2(a0, *(__half2*)&u6.x); a1 = __hadd2(a1, *(__half2*)&u6.y);
            a2 = __hadd2(a2, *(__half2*)&u6.z); a3 = __hadd2(a3, *(__half2*)&u6.w);
            a0 = __hadd2(a0, *(__half2*)&u7.x); a1 = __hadd2(a1, *(__half2*)&u7.y);
            a2 = __hadd2(a2, *(__half2*)&u7.z); a3 = __hadd2(a3, *(__half2*)&u7.w);
        }
        float2 t0 = __half22float2(a0); f0 += t0.x; f1 += t0.y;
        float2 t1 = __half22float2(a1); f2 += t1.x; f3 += t1.y;
        float2 t2 = __half22float2(a2); f4 += t2.x; f5 += t2.y;
        float2 t3 = __half22float2(a3); f6 += t3.x; f7 += t3.y;
    }
    f0 += __shfl_xor(f0,16); f1 += __shfl_xor(f1,16); f2 += __shfl_xor(f2,16); f3 += __shfl_xor(f3,16);
    f4 += __shfl_xor(f4,16); f5 += __shfl_xor(f5,16); f6 += __shfl_xor(f6,16); f7 += __shfl_xor(f7,16);
    f0 += __shfl_xor(f0,32); f1 += __shfl_xor(f1,32); f2 += __shfl_xor(f2,32); f3 += __shfl_xor(f3,32);
    f4 += __shfl_xor(f4,32); f5 += __shfl_xor(f5,32); f6 += __shfl_xor(f6,32); f7 += __shfl_xor(f7,32);
    if (q == 0){
        uint4 su = *(const uint4*)(yb + (((unsigned)wid<<8) + lofs));   // self loop
        float2 s0 = __half22float2(*(__half2*)&su.x); f0 += s0.x; f1 += s0.y;
        float2 s1 = __half22float2(*(__half2*)&su.y); f2 += s1.x; f3 += s1.y;
        float2 s2 = __half22float2(*(__half2*)&su.z); f4 += s2.x; f5 += s2.y;
        float2 s3 = __half22float2(*(__half2*)&su.w); f6 += s3.x; f7 += s3.y;
        float dv = dinv[wid];
        float4 ba = ld4(&b1[ql*8]), bb = ld4(&b1[ql*8+4]);
        float o0 = dv*f0+ba.x, o1 = dv*f1+ba.y, o2 = dv*f2+ba.z, o3 = dv*f3+ba.w;
        float o4 = dv*f4+bb.x, o5 = dv*f5+bb.y, o6 = dv*f6+bb.z, o7 = dv*f7+bb.w;
        o0 = o0>0.f?o0:expm1f(o0); o1 = o1>0.f?o1:expm1f(o1);
        o2 = o2>0.f?o2:expm1f(o2); o3 = o3>0.f?o3:expm1f(o3);
        o4 = o4>0.f?o4:expm1f(o4); o5 = o5>0.f?o5:expm1f(o5);
        o6 = o6>0.f?o6:expm1f(o6); o7 = o7>0.f?o7:expm1f(o7);
        __half2 p0 = __floats2half2_rn(o0,o1), p1 = __floats2half2_rn(o2,o3);
        __half2 p2 = __floats2half2_rn(o4,o5), p3 = __floats2half2_rn(o6,o7);
        uint4 stv; stv.x=*(unsigned*)&p0; stv.y=*(unsigned*)&p1; stv.z=*(unsigned*)&p2; stv.w=*(unsigned*)&p3;
        *reinterpret_cast<uint4*>(&h[(size_t)wid*128 + ql*8]) = stv;
    }
}

// ---------------- mean-pool partial sums (streaming, few atomics) ----------------
__global__ void k_mpoolh(const __half* __restrict__ hsrc, const int* __restrict__ gstart,
                         float* __restrict__ msum){
    int g = blockIdx.x, part = blockIdx.y, P = gridDim.y;
    int c = threadIdx.x;   // 64 threads, half2 cols
    int s0 = gstart[g], s1 = gstart[g+1];
    int len = s1 - s0;
    int per = (len + P - 1) / P;
    int rbeg = s0 + part*per, rend = rbeg + per; if (rend > s1) rend = s1;
    float sx = 0.f, sy = 0.f;
    const __half2* h2 = (const __half2*)hsrc;
    for (int r = rbeg; r < rend; ++r){
        float2 f = __half22float2(h2[(size_t)r*64 + c]);
        sx += f.x; sy += f.y;
    }
    if (rend > rbeg){
        atomicAdd(&msum[g*128 + 2*c], sx);
        atomicAdd(&msum[g*128 + 2*c+1], sy);
    }
}

__global__ void k_mpool(const float* __restrict__ srcm, const int* __restrict__ gstart,
                        float* __restrict__ msum, int C){
    int g = blockIdx.x, part = blockIdx.y, P = gridDim.y;
    int c = threadIdx.x;
    if (c >= C) return;
    int s0 = gstart[g], s1 = gstart[g+1];
    int len = s1 - s0;
    int per = (len + P - 1) / P;
    int rbeg = s0 + part*per, rend = rbeg + per; if (rend > s1) rend = s1;
    float sum = 0.f;
    for (int r = rbeg; r < rend; ++r) sum += srcm[(size_t)r*C + c];
    if (rend > rbeg) atomicAdd(&msum[g*C + c], sum);
}

__global__ void k_mlp1(const float* __restrict__ msum, const int* __restrict__ gstart,
                       const float* __restrict__ mW1, const float* __restrict__ mb1,
                       __half* __restrict__ r1h){
    int g = blockIdx.x, c = threadIdx.x;   // 128 threads
    int cnt = gstart[g+1] - gstart[g];
    float inv = 1.f / (float)(cnt > 1 ? cnt : 1);
    float acc = mb1[c];
    for (int k=0;k<128;k++) acc = fmaf(msum[g*128+k]*inv, mW1[k*128+c], acc);
    r1h[g*128+c] = __float2half(fmaxf(acc, 0.f));
}

__global__ void k_mlp2(const float* __restrict__ msum2, const int* __restrict__ gstart,
                       const float* __restrict__ mW2, const float* __restrict__ mb2,
                       float* __restrict__ r2){
    int g = blockIdx.x, c = threadIdx.x;
    if (c >= 32) return;
    int cnt = gstart[g+1] - gstart[g];
    float inv = 1.f / (float)(cnt > 1 ? cnt : 1);
    float acc = mb2[c];
    for (int k=0;k<32;k++) acc = fmaf(msum2[g*32+k]*inv, mW2[k*32+c], acc);
    r2[g*32+c] = fmaxf(acc, 0.f);
}

// ---------------- GEMM2 (MFMA fp16): y2 = ((h + r1h[batch]) @ W2) * dinv ----------------
__global__ __launch_bounds__(256) void k_gemm2(const __half* __restrict__ h, const __half* __restrict__ r1h,
                                               const int* __restrict__ batch, const __half* __restrict__ w2t,
                                               const float* __restrict__ dinv, __half* __restrict__ y2, int N){
    __shared__ __half Wl[32*136];
    int t = threadIdx.x;
    if (blockIdx.x==0 && t < 8)
        reinterpret_cast<uint2*>(y2 + (size_t)N*32)[t] = make_uint2(0u,0u);
    {
        const uint4* g = (const uint4*)w2t;
        uint4* l = (uint4*)Wl;
        for (int i = t; i < 544; i += 256) l[i] = g[i];
    }
    __syncthreads();
    int wv = t>>6, lane = t&63;
    int r0 = blockIdx.x*64 + wv*16;
    if (r0 >= N) return;
    int lr = lane & 15, lg = lane >> 4;
    int r = r0 + lr;
    bool rok = r < N;
    int rr = rok ? r : 0;
    const __half* hrow = h + (size_t)rr*128;
    const __half* vrow = r1h + (size_t)batch[rr]*128;
    floatx4 acc0 = (floatx4){0.f,0.f,0.f,0.f};
    floatx4 acc1 = (floatx4){0.f,0.f,0.f,0.f};
    #pragma unroll
    for (int ks=0; ks<4; ks++){
        int k0 = ks*32 + lg*8;
        uint4 hu = *reinterpret_cast<const uint4*>(hrow + k0);
        uint4 vu = *reinterpret_cast<const uint4*>(vrow + k0);
        __half2 b0 = __hadd2(*(__half2*)&hu.x, *(__half2*)&vu.x);
        __half2 b1_ = __hadd2(*(__half2*)&hu.y, *(__half2*)&vu.y);
        __half2 b2_ = __hadd2(*(__half2*)&hu.z, *(__half2*)&vu.z);
        __half2 b3_ = __hadd2(*(__half2*)&hu.w, *(__half2*)&vu.w);
        uint4 bu; bu.x=*(unsigned*)&b0; bu.y=*(unsigned*)&b1_; bu.z=*(unsigned*)&b2_; bu.w=*(unsigned*)&b3_;
        half8 bfrag = *reinterpret_cast<half8*>(&bu);
        half8 a0 = *reinterpret_cast<const half8*>(&Wl[(0*16 + lr)*136 + k0]);
        half8 a1 = *reinterpret_cast<const half8*>(&Wl[(1*16 + lr)*136 + k0]);
        acc0 = __builtin_amdgcn_mfma_f32_16x16x32_f16(a0, bfrag, acc0, 0, 0, 0);
        acc1 = __builtin_amdgcn_mfma_f32_16x16x32_f16(a1, bfrag, acc1, 0, 0, 0);
    }
    if (rok){
        float dv = dinv[r];
        {
            __half2 p0 = __floats2half2_rn(acc0[0]*dv, acc0[1]*dv);
            __half2 p1 = __floats2half2_rn(acc0[2]*dv, acc0[3]*dv);
            uint2 stv; stv.x = *(unsigned*)&p0; stv.y = *(unsigned*)&p1;
            *reinterpret_cast<uint2*>(&y2[(size_t)r*32 + 0 + lg*4]) = stv;
        }
        {
            __half2 p0 = __floats2half2_rn(acc1[0]*dv, acc1[1]*dv);
            __half2 p1 = __floats2half2_rn(acc1[2]*dv, acc1[3]*dv);
            uint2 stv; stv.x = *(unsigned*)&p0; stv.y = *(unsigned*)&p1;
            *reinterpret_cast<uint2*>(&y2[(size_t)r*32 + 16 + lg*4]) = stv;
        }
    }
}

// ---------------- layer-2 aggregation: octet-wave 8B gathers, 32-bit offsets, 8-deep ILP ----------------
__global__ void k_agg2h(const __half* __restrict__ y2, const float* __restrict__ dinv,
                        const float* __restrict__ b2, const int* __restrict__ rs,
                        const unsigned short* __restrict__ csr, float* __restrict__ Z, int N){
    int wid = (int)((blockIdx.x*blockDim.x + threadIdx.x) >> 6);
    if (wid >= N) return;
    int lane = threadIdx.x & 63;
    int o8 = lane >> 3, ol = lane & 7;
    int beg = rs[wid], end = rs[wid+1], len = end-beg;
    int olen = (len + 7) >> 3;
    int obeg = beg + o8*olen;
    int oend = obeg + olen; if (oend > end) oend = end;
    int mylen = oend - obeg; if (mylen < 0) mylen = 0;
    const char* yb = (const char*)y2;
    unsigned lofs = (unsigned)ol * 8u;
    float f0=0.f, f1=0.f, f2=0.f, f3=0.f;
    int iters = (olen + 7) >> 3;
    for (int c=0;c<iters;c++){
        int o = c*8 + ol;
        int idx = (o < mylen) ? (int)csr[obeg + o] : N;
        int tb = o8<<3;
        int s0 = __shfl(idx, tb+0);
        int s1 = __shfl(idx, tb+1);
        int s2 = __shfl(idx, tb+2);
        int s3 = __shfl(idx, tb+3);
        int s4 = __shfl(idx, tb+4);
        int s5 = __shfl(idx, tb+5);
        int s6 = __shfl(idx, tb+6);
        int s7 = __shfl(idx, tb+7);
        uint2 u0 = *(const uint2*)(yb + (((unsigned)s0<<6) + lofs));
        uint2 u1 = *(const uint2*)(yb + (((unsigned)s1<<6) + lofs));
        uint2 u2 = *(const uint2*)(yb + (((unsigned)s2<<6) + lofs));
        uint2 u3 = *(const uint2*)(yb + (((unsigned)s3<<6) + lofs));
        uint2 u4 = *(const uint2*)(yb + (((unsigned)s4<<6) + lofs));
        uint2 u5 = *(const uint2*)(yb + (((unsigned)s5<<6) + lofs));
        uint2 u6 = *(const uint2*)(yb + (((unsigned)s6<<6) + lofs));
        uint2 u7 = *(const uint2*)(yb + (((unsigned)s7<<6) + lofs));
        __half2 a0 = __float2half2_rn(0.f), a1 = a0;
        a0 = __hadd2(a0, *(__half2*)&u0.x); a1 = __hadd2(a1, *(__half2*)&u0.y);
        a0 = __hadd2(a0, *(__half2*)&u1.x); a1 = __hadd2(a1, *(__half2*)&u1.y);
        a0 = __hadd2(a0, *(__half2*)&u2.x); a1 = __hadd2(a1, *(__half2*)&u2.y);
        a0 = __hadd2(a0, *(__half2*)&u3.x); a1 = __hadd2(a1, *(__half2*)&u3.y);
        a0 = __hadd2(a0, *(__half2*)&u4.x); a1 = __hadd2(a1, *(__half2*)&u4.y);
        a0 = __hadd2(a0, *(__half2*)&u5.x); a1 = __hadd2(a1, *(__half2*)&u5.y);
        a0 = __hadd2(a0, *(__half2*)&u6.x); a1 = __hadd2(a1, *(__half2*)&u6.y);
        a0 = __hadd2(a0, *(__half2*)&u7.x); a1 = __hadd2(a1, *(__half2*)&u7.y);
        float2 t0 = __half22float2(a0); f0 += t0.x; f1 += t0.y;
        float2 t1 = __half22float2(a1); f2 += t1.x; f3 += t1.y;
    }
    f0 += __shfl_xor(f0,8);  f1 += __shfl_xor(f1,8);  f2 += __shfl_xor(f2,8);  f3 += __shfl_xor(f3,8);
    f0 += __shfl_xor(f0,16); f1 += __shfl_xor(f1,16); f2 += __shfl_xor(f2,16); f3 += __shfl_xor(f3,16);
    f0 += __shfl_xor(f0,32); f1 += __shfl_xor(f1,32); f2 += __shfl_xor(f2,32); f3 += __shfl_xor(f3,32);
    if (o8 == 0){
        uint2 su = *(const uint2*)(yb + (((unsigned)wid<<6) + lofs));   // self loop
        float2 s0 = __half22float2(*(__half2*)&su.x); f0 += s0.x; f1 += s0.y;
        float2 s1 = __half22float2(*(__half2*)&su.y); f2 += s1.x; f3 += s1.y;
        float dv = dinv[wid];
        float4 bb = ld4(&b2[ol*4]);
        float4 outv;
        outv.x = dv*f0 + bb.x; outv.y = dv*f1 + bb.y;
        outv.z = dv*f2 + bb.z; outv.w = dv*f3 + bb.w;
        *reinterpret_cast<float4*>(&Z[(size_t)wid*32 + ol*4]) = outv;
    }
}

// ---------------- + virtual node + softmax (in-place on d_out) ----------------
__global__ void k_softmax(float* __restrict__ Z, const float* __restrict__ r2,
                          const int* __restrict__ batch, int N){
    int r = blockIdx.x*8 + (threadIdx.x>>5);
    int c = threadIdx.x & 31;
    if (r >= N) return;
    float z = Z[(size_t)r*32+c] + r2[batch[r]*32 + c];
    float m = z;
    #pragma unroll
    for (int off=16; off>=1; off>>=1) m = fmaxf(m, __shfl_xor(m, off));
    float e = expf(z - m);
    float s = e;
    #pragma unroll
    for (int off=16; off>=1; off>>=1) s += __shfl_xor(s, off);
    Z[(size_t)r*32+c] = e / s;
}

extern "C" void kernel_launch(void* const* d_in, const int* in_sizes, int n_in,
                              void* d_out, int out_size, void* d_ws, size_t ws_size,
                              hipStream_t stream){
    const float* X   = (const float*)d_in[0];
    const float* W1  = (const float*)d_in[1];
    const float* b1  = (const float*)d_in[2];
    const float* W2  = (const float*)d_in[3];
    const float* b2  = (const float*)d_in[4];
    const float* mW1 = (const float*)d_in[5];
    const float* mb1 = (const float*)d_in[6];
    const float* mW2 = (const float*)d_in[7];
    const float* mb2 = (const float*)d_in[8];
    const int*   ei  = (const int*)d_in[9];
    const int*   batch = (const int*)d_in[10];
    int N = in_sizes[0] / 128;
    int E = in_sizes[9] / 2;
    const int* src = ei;
    const int* dst = ei + E;
    float* Zout = (float*)d_out;

    char* wsp = (char*)d_ws;
    size_t off = 0;
    auto alloc = [&](size_t bytes)->char*{
        char* p = wsp + off; off += (bytes + 255) & ~(size_t)255; return p;
    };
    // zero zone
    int*   bcnt  = (int*)  alloc((size_t)MAXNB*4);
    int*   bfill = (int*)  alloc((size_t)MAXNB*4);
    float* msum  = (float*)alloc((size_t)GNUM*128*4);
    float* msum2 = (float*)alloc((size_t)GNUM*32*4);
    size_t zero_bytes = off;
    // rest
    int*   bbase = (int*)  alloc((size_t)(MAXNB+1)*4);
    int*   rs    = (int*)  alloc((size_t)(N+1)*4);
    int*   gstart= (int*)  alloc((GNUM+1)*4);
    unsigned* ebuf = (unsigned*)alloc((size_t)E*4);
    unsigned short* csr = (unsigned short*)alloc((size_t)E*2);
    float* dinvp = (float*)alloc((size_t)N*4);
    __half* w1t  = (__half*)alloc((size_t)W1T_ELEMS*2);
    __half* w2t  = (__half*)alloc((size_t)W2T_ELEMS*2);
    __half* yh   = (__half*)alloc((size_t)(N+1)*128*2);   // +1: zero row
    __half* h    = (__half*)alloc((size_t)N*128*2);
    __half* y2h  = (__half*)alloc((size_t)(N+1)*32*2);    // +1: zero row
    __half* r1buf= (__half*)alloc((size_t)GNUM*128*2);
    float* r2buf = (float*)alloc((size_t)GNUM*32*4);
    (void)ws_size; (void)n_in; (void)out_size;

    hipMemsetAsync(d_ws, 0, zero_bytes, stream);

    int NB = (N + 127) >> 7;            // 391
    int EB = (E + CHUNK-1) / CHUNK;     // 391
    int PREP = (W1T_ELEMS + W2T_ELEMS + 255)/256;   // 85

    k_hist         <<<EB + PREP, 256, 0, stream>>>(dst, E, NB, bcnt, W1, W2, w1t, w2t, EB);
    k_scan1b       <<<1, 256, 0, stream>>>(bcnt, bbase, NB, E, batch, N, gstart);
    k_scatter      <<<EB, 256, 0, stream>>>(src, dst, E, NB, bbase, bfill, ebuf);
    k_bucket_finish<<<NB, 256, 0, stream>>>(ebuf, bbase, rs, csr, dinvp, N, E);

    k_gemm1 <<<(N+63)/64, 256, 0, stream>>>(X, w1t, dinvp, yh, N);
    k_agg1  <<<(N+3)/4, 256, 0, stream>>>(yh, dinvp, b1, rs, csr, h, N);

    k_mpoolh<<<dim3(GNUM,8), 64, 0, stream>>>(h, gstart, msum);
    k_mlp1  <<<GNUM, 128, 0, stream>>>(msum, gstart, mW1, mb1, r1buf);

    k_gemm2 <<<(N+63)/64, 256, 0, stream>>>(h, r1buf, batch, w2t, dinvp, y2h, N);
    k_agg2h <<<(N+3)/4, 256, 0, stream>>>(y2h, dinvp, b2, rs, csr, Zout, N);

    k_mpool <<<dim3(GNUM,8), 64, 0, stream>>>(Zout, gstart, msum2, 32);
    k_mlp2  <<<GNUM, 64, 0, stream>>>(msum2, gstart, mW2, mb2, r2buf);
    k_softmax<<<(N+7)/8, 256, 0, stream>>>(Zout, r2buf, batch, N);
}

// Round 10
// 210.639 us; speedup vs baseline: 2.4930x; 1.0775x over previous
//
#include <hip/hip_runtime.h>
#include <hip/hip_bf16.h>
#include <hip/hip_fp16.h>

#define DEV_INLINE __device__ __forceinline__

static DEV_INLINE float4 ld4(const float* p){ return *reinterpret_cast<const float4*>(p); }

#define GNUM 64
#define CHUNK 4096
#define MAXNB 1024   // bucket = dst>>7; N <= 65536 (u16 packing)
#define CAP 8192     // fixed per-bucket capacity (mean ~4096, +64 sigma headroom)

typedef _Float16 half8 __attribute__((ext_vector_type(8)));
typedef float floatx4 __attribute__((ext_vector_type(4)));

#define W1T_ELEMS (128*136)   // 17408
#define W2T_ELEMS (32*136)    // 4352

// ======================= single-pass bucketed edge build (+ fused weight prep) =======================
// No histogram pass: per-block LDS counts -> direct global reservation into fixed-CAP buckets.
__global__ __launch_bounds__(256) void k_scatter(const int* __restrict__ src, const int* __restrict__ dst,
                                                 int E, int NB, int* __restrict__ bfill,
                                                 unsigned* __restrict__ ebuf,
                                                 const float* __restrict__ W1, const float* __restrict__ W2,
                                                 __half* __restrict__ w1t, __half* __restrict__ w2t, int EB){
    if ((int)blockIdx.x >= EB){   // weight-prep tail blocks
        int f = ((int)blockIdx.x - EB)*256 + threadIdx.x;
        if (f < W1T_ELEMS){
            int c = f/136, k = f - c*136;
            w1t[f] = (k<128) ? __float2half(W1[k*128+c]) : __float2half(0.f);
        } else {
            int f2 = f - W1T_ELEMS;
            if (f2 < W2T_ELEMS){
                int c = f2/136, k = f2 - c*136;
                w2t[f2] = (k<128) ? __float2half(W2[k*32+c]) : __float2half(0.f);
            }
        }
        return;
    }
    __shared__ int cnt[MAXNB];
    __shared__ int pfx[MAXNB];
    __shared__ int gbase[MAXNB];
    __shared__ unsigned stage[CHUNK];
    __shared__ int ws[4];
    int t = threadIdx.x; int base0 = blockIdx.x*CHUNK;
    int tot = E - base0; if (tot > CHUNK) tot = CHUNK;
    for (int i=t;i<NB;i+=256) cnt[i]=0;
    __syncthreads();
    unsigned v[16]; int rk[16];
    #pragma unroll
    for (int k=0;k<16;k++){
        int o = t + k*256;
        if (o < tot){
            int e = base0 + o;
            int s = src[e], d = dst[e];
            v[k] = (unsigned)s | ((unsigned)d<<16);
            rk[k] = atomicAdd(&cnt[d>>7], 1);
        } else { v[k]=0u; rk[k]=-1; }
    }
    __syncthreads();
    int i0 = t*4;
    int c0=(i0+0<NB)?cnt[i0+0]:0, c1=(i0+1<NB)?cnt[i0+1]:0;
    int c2=(i0+2<NB)?cnt[i0+2]:0, c3=(i0+3<NB)?cnt[i0+3]:0;
    int tsum=c0+c1+c2+c3;
    int lane=t&63, w=t>>6;
    int x=tsum;
    for (int off=1;off<64;off<<=1){ int yv=__shfl_up(x,off); if (lane>=off) x+=yv; }
    if (lane==63) ws[w]=x;
    __syncthreads();
    if (t==0){ int a=0; for (int i=0;i<4;i++){ int tmp=ws[i]; ws[i]=a; a+=tmp; } }
    __syncthreads();
    int ex = x - tsum + ws[w];
    if (i0+0<NB) pfx[i0+0]=ex; ex+=c0;
    if (i0+1<NB) pfx[i0+1]=ex; ex+=c1;
    if (i0+2<NB) pfx[i0+2]=ex; ex+=c2;
    if (i0+3<NB) pfx[i0+3]=ex;
    __syncthreads();
    for (int i=t;i<NB;i+=256){
        int c = cnt[i];
        if (c){
            int base = atomicAdd(&bfill[i], c);
            if (base > CAP - c) base = CAP - c;   // defensive clamp (never expected)
            gbase[i] = i*CAP + base;
        } else gbase[i] = 0;
    }
    __syncthreads();
    #pragma unroll
    for (int k=0;k<16;k++) if (rk[k]>=0){ int b = (int)(v[k]>>23); stage[pfx[b]+rk[k]] = v[k]; }
    __syncthreads();
    for (int j=t;j<tot;j+=256){
        unsigned u = stage[j];
        int b = (int)(u>>23);
        ebuf[gbase[b] + (j - pfx[b])] = u;
    }
}

// fused: per-bucket degree count -> in-LDS prefix -> rs2(start,end) + dinv -> CSR (u16) fill
// block 0 threads 128..192 also compute graph boundaries (batch sorted).
__global__ __launch_bounds__(256) void k_bucket_finish(const unsigned* __restrict__ ebuf,
                                                       const int* __restrict__ bfill,
                                                       int2* __restrict__ rs2, unsigned short* __restrict__ csr,
                                                       float* __restrict__ dinv,
                                                       const int* __restrict__ batch, int* __restrict__ gstart,
                                                       int N){
    __shared__ int c2[128];
    __shared__ int rsl[128];
    __shared__ int ws[4];
    int b = blockIdx.x, t = threadIdx.x;
    if (b == 0 && t >= 128 && t < 128 + GNUM + 1){
        int g = t - 128;
        int lo = 0, hi = N;
        while (lo < hi){ int mid = (lo+hi)>>1; if (batch[mid] < g) lo = mid+1; else hi = mid; }
        gstart[g] = lo;
    }
    if (t < 128) c2[t] = 0;
    __syncthreads();
    int s0 = b*CAP;
    int cntB = bfill[b]; if (cntB > CAP) cntB = CAP;
    int s1 = s0 + cntB;
    for (int j = s0+t; j < s1; j += 256)
        atomicAdd(&c2[(ebuf[j]>>16)&127], 1);
    __syncthreads();
    int v = (t < 128) ? c2[t] : 0;
    int lane = t & 63, w = t >> 6;
    int x = v;
    for (int off=1; off<64; off<<=1){
        int yv = __shfl_up(x, off);
        if (lane >= off) x += yv;
    }
    if (lane == 63) ws[w] = x;
    __syncthreads();
    if (t < 128){
        int ex = x - v + ((w == 1) ? ws[0] : 0);
        rsl[t] = s0 + ex;
        int node = (b<<7) + t;
        if (node < N){
            rs2[node] = make_int2(s0 + ex, s0 + ex + v);
            dinv[node] = rsqrtf((float)(v + 1));
        }
    }
    __syncthreads();
    if (t < 128) c2[t] = 0;
    __syncthreads();
    for (int j = s0+t; j < s1; j += 256){
        unsigned u = ebuf[j];
        int ld = (u>>16)&127;
        int p = atomicAdd(&c2[ld], 1);
        csr[rsl[ld]+p] = (unsigned short)(u & 0xffffu);
    }
}

// ---------------- GEMM1 (MFMA fp16): y = (X @ W1) * dinv[row], fp16 out ----------------
__global__ __launch_bounds__(256) void k_gemm1(const float* __restrict__ X, const __half* __restrict__ w1t,
                                               const float* __restrict__ dinv, __half* __restrict__ yh, int N){
    __shared__ __half Wl[128*136];
    int t = threadIdx.x;
    if (blockIdx.x==0 && t < 32)
        reinterpret_cast<uint2*>(yh + (size_t)N*128)[t] = make_uint2(0u,0u);
    {
        const uint4* g = (const uint4*)w1t;
        uint4* l = (uint4*)Wl;
        for (int i = t; i < 2176; i += 256) l[i] = g[i];
    }
    __syncthreads();
    int wv = t>>6, lane = t&63;
    int r0 = blockIdx.x*64 + wv*16;
    if (r0 >= N) return;
    int lr = lane & 15, lg = lane >> 4;
    int r = r0 + lr;
    bool rok = r < N;
    const float* xrow = X + (size_t)(rok ? r : 0)*128;
    floatx4 acc[8];
    #pragma unroll
    for (int i=0;i<8;i++) acc[i] = (floatx4){0.f,0.f,0.f,0.f};
    #pragma unroll
    for (int ks=0; ks<4; ks++){
        int k0 = ks*32 + lg*8;
        float4 xa = ld4(xrow + k0);
        float4 xb = ld4(xrow + k0 + 4);
        half8 bfrag;
        bfrag[0]=(_Float16)xa.x; bfrag[1]=(_Float16)xa.y; bfrag[2]=(_Float16)xa.z; bfrag[3]=(_Float16)xa.w;
        bfrag[4]=(_Float16)xb.x; bfrag[5]=(_Float16)xb.y; bfrag[6]=(_Float16)xb.z; bfrag[7]=(_Float16)xb.w;
        #pragma unroll
        for (int ct=0; ct<8; ct++){
            half8 afrag = *reinterpret_cast<const half8*>(&Wl[(ct*16 + lr)*136 + k0]);
            acc[ct] = __builtin_amdgcn_mfma_f32_16x16x32_f16(afrag, bfrag, acc[ct], 0, 0, 0);
        }
    }
    if (rok){
        float dv = dinv[r];
        #pragma unroll
        for (int ct=0; ct<8; ct++){
            __half2 p0 = __floats2half2_rn(acc[ct][0]*dv, acc[ct][1]*dv);
            __half2 p1 = __floats2half2_rn(acc[ct][2]*dv, acc[ct][3]*dv);
            uint2 stv; stv.x = *(unsigned*)&p0; stv.y = *(unsigned*)&p1;
            *reinterpret_cast<uint2*>(&yh[(size_t)r*128 + ct*16 + lg*4]) = stv;
        }
    }
}

// ---------------- layer-1 aggregation: quarter-wave 16B gathers, zero-row, fp16 accum ----------------
__global__ void k_agg1(const __half* __restrict__ yh, const float* __restrict__ dinv,
                       const float* __restrict__ b1, const int2* __restrict__ rs2,
                       const unsigned short* __restrict__ csr, __half* __restrict__ h, int N){
    int wid = (int)((blockIdx.x * blockDim.x + threadIdx.x) >> 6);
    if (wid >= N) return;
    int lane = threadIdx.x & 63;
    int q = lane >> 4, ql = lane & 15;
    int2 se = rs2[wid];
    int beg = se.x, end = se.y;
    int len = end - beg;
    int qlen = (len + 3) >> 2;
    int qbeg = beg + q*qlen;
    int qend = qbeg + qlen; if (qend > end) qend = end;
    int mylen = qend - qbeg; if (mylen < 0) mylen = 0;
    const char* yb = (const char*)yh;
    unsigned lofs = (unsigned)ql * 16u;
    float f0=0.f,f1=0.f,f2=0.f,f3=0.f,f4=0.f,f5=0.f,f6=0.f,f7=0.f;
    int iters = (qlen + 15) >> 4;
    for (int c=0;c<iters;c++){
        int o = c*16 + ql;
        int idx = (o < mylen) ? (int)csr[qbeg + o] : N;   // N = zero row
        int tmax = qlen - c*16; if (tmax > 16) tmax = 16;
        int nch = (tmax + 7) >> 3;
        __half2 a0 = __float2half2_rn(0.f), a1 = a0, a2 = a0, a3 = a0;
        for (int ch=0; ch<nch; ++ch){
            int tb = (q<<4) + ch*8;
            int s0 = __shfl(idx, tb+0);
            int s1 = __shfl(idx, tb+1);
            int s2 = __shfl(idx, tb+2);
            int s3 = __shfl(idx, tb+3);
            int s4 = __shfl(idx, tb+4);
            int s5 = __shfl(idx, tb+5);
            int s6 = __shfl(idx, tb+6);
            int s7 = __shfl(idx, tb+7);
            uint4 u0 = *(const uint4*)(yb + (((unsigned)s0<<8) + lofs));
            uint4 u1 = *(const uint4*)(yb + (((unsigned)s1<<8) + lofs));
            uint4 u2 = *(const uint4*)(yb + (((unsigned)s2<<8) + lofs));
            uint4 u3 = *(const uint4*)(yb + (((unsigned)s3<<8) + lofs));
            uint4 u4 = *(const uint4*)(yb + (((unsigned)s4<<8) + lofs));
            uint4 u5 = *(const uint4*)(yb + (((unsigned)s5<<8) + lofs));
            uint4 u6 = *(const uint4*)(yb + (((unsigned)s6<<8) + lofs));
            uint4 u7 = *(const uint4*)(yb + (((unsigned)s7<<8) + lofs));
            a0 = __hadd2(a0, *(__half2*)&u0.x); a1 = __hadd2(a1, *(__half2*)&u0.y);
            a2 = __hadd2(a2, *(__half2*)&u0.z); a3 = __hadd2(a3, *(__half2*)&u0.w);
            a0 = __hadd2(a0, *(__half2*)&u1.x); a1 = __hadd2(a1, *(__half2*)&u1.y);
            a2 = __hadd2(a2, *(__half2*)&u1.z); a3 = __hadd2(a3, *(__half2*)&u1.w);
            a0 = __hadd2(a0, *(__half2*)&u2.x); a1 = __hadd2(a1, *(__half2*)&u2.y);
            a2 = __hadd2(a2, *(__half2*)&u2.z); a3 = __hadd2(a3, *(__half2*)&u2.w);
            a0 = __hadd2(a0, *(__half2*)&u3.x); a1 = __hadd2(a1, *(__half2*)&u3.y);
            a2 = __hadd2(a2, *(__half2*)&u3.z); a3 = __hadd2(a3, *(__half2*)&u3.w);
            a0 = __hadd2(a0, *(__half2*)&u4.x); a1 = __hadd2(a1, *(__half2*)&u4.y);
            a2 = __hadd2(a2, *(__half2*)&u4.z); a3 = __hadd2(a3, *(__half2*)&u4.w);
            a0 = __hadd2(a0, *(__half2*)&u5.x); a1 = __hadd2(a1, *(__half2*)&u5.y);
            a2 = __hadd2(a2, *(__half2*)&u5.z); a3 = __hadd2(a3, *(__half2*)&u5.w);
            a0 = __hadd2(a0, *(__half2*)&u6.x); a1 = __hadd2(a1, *(__half2*)&u6.y);
            a2 = __hadd2(a2, *(__half2*)&u6.z); a3 = __hadd2(a3, *(__half2*)&u6.w);
            a0 = __hadd2(a0, *(__half2*)&u7.x); a1 = __hadd2(a1, *(__half2*)&u7.y);
            a2 = __hadd2(a2, *(__half2*)&u7.z); a3 = __hadd2(a3, *(__half2*)&u7.w);
        }
        float2 t0 = __half22float2(a0); f0 += t0.x; f1 += t0.y;
        float2 t1 = __half22float2(a1); f2 += t1.x; f3 += t1.y;
        float2 t2 = __half22float2(a2); f4 += t2.x; f5 += t2.y;
        float2 t3 = __half22float2(a3); f6 += t3.x; f7 += t3.y;
    }
    f0 += __shfl_xor(f0,16); f1 += __shfl_xor(f1,16); f2 += __shfl_xor(f2,16); f3 += __shfl_xor(f3,16);
    f4 += __shfl_xor(f4,16); f5 += __shfl_xor(f5,16); f6 += __shfl_xor(f6,16); f7 += __shfl_xor(f7,16);
    f0 += __shfl_xor(f0,32); f1 += __shfl_xor(f1,32); f2 += __shfl_xor(f2,32); f3 += __shfl_xor(f3,32);
    f4 += __shfl_xor(f4,32); f5 += __shfl_xor(f5,32); f6 += __shfl_xor(f6,32); f7 += __shfl_xor(f7,32);
    if (q == 0){
        uint4 su = *(const uint4*)(yb + (((unsigned)wid<<8) + lofs));   // self loop
        float2 s0 = __half22float2(*(__half2*)&su.x); f0 += s0.x; f1 += s0.y;
        float2 s1 = __half22float2(*(__half2*)&su.y); f2 += s1.x; f3 += s1.y;
        float2 s2 = __half22float2(*(__half2*)&su.z); f4 += s2.x; f5 += s2.y;
        float2 s3 = __half22float2(*(__half2*)&su.w); f6 += s3.x; f7 += s3.y;
        float dv = dinv[wid];
        float4 ba = ld4(&b1[ql*8]), bb = ld4(&b1[ql*8+4]);
        float o0 = dv*f0+ba.x, o1 = dv*f1+ba.y, o2 = dv*f2+ba.z, o3 = dv*f3+ba.w;
        float o4 = dv*f4+bb.x, o5 = dv*f5+bb.y, o6 = dv*f6+bb.z, o7 = dv*f7+bb.w;
        o0 = o0>0.f?o0:expm1f(o0); o1 = o1>0.f?o1:expm1f(o1);
        o2 = o2>0.f?o2:expm1f(o2); o3 = o3>0.f?o3:expm1f(o3);
        o4 = o4>0.f?o4:expm1f(o4); o5 = o5>0.f?o5:expm1f(o5);
        o6 = o6>0.f?o6:expm1f(o6); o7 = o7>0.f?o7:expm1f(o7);
        __half2 p0 = __floats2half2_rn(o0,o1), p1 = __floats2half2_rn(o2,o3);
        __half2 p2 = __floats2half2_rn(o4,o5), p3 = __floats2half2_rn(o6,o7);
        uint4 stv; stv.x=*(unsigned*)&p0; stv.y=*(unsigned*)&p1; stv.z=*(unsigned*)&p2; stv.w=*(unsigned*)&p3;
        *reinterpret_cast<uint4*>(&h[(size_t)wid*128 + ql*8]) = stv;
    }
}

// ---------------- mean-pool partial sums (streaming, few atomics) ----------------
__global__ void k_mpoolh(const __half* __restrict__ hsrc, const int* __restrict__ gstart,
                         float* __restrict__ msum){
    int g = blockIdx.x, part = blockIdx.y, P = gridDim.y;
    int c = threadIdx.x;   // 64 threads, half2 cols
    int s0 = gstart[g], s1 = gstart[g+1];
    int len = s1 - s0;
    int per = (len + P - 1) / P;
    int rbeg = s0 + part*per, rend = rbeg + per; if (rend > s1) rend = s1;
    float sx = 0.f, sy = 0.f;
    const __half2* h2 = (const __half2*)hsrc;
    for (int r = rbeg; r < rend; ++r){
        float2 f = __half22float2(h2[(size_t)r*64 + c]);
        sx += f.x; sy += f.y;
    }
    if (rend > rbeg){
        atomicAdd(&msum[g*128 + 2*c], sx);
        atomicAdd(&msum[g*128 + 2*c+1], sy);
    }
}

__global__ void k_mpool(const float* __restrict__ srcm, const int* __restrict__ gstart,
                        float* __restrict__ msum, int C){
    int g = blockIdx.x, part = blockIdx.y, P = gridDim.y;
    int c = threadIdx.x;
    if (c >= C) return;
    int s0 = gstart[g], s1 = gstart[g+1];
    int len = s1 - s0;
    int per = (len + P - 1) / P;
    int rbeg = s0 + part*per, rend = rbeg + per; if (rend > s1) rend = s1;
    float sum = 0.f;
    for (int r = rbeg; r < rend; ++r) sum += srcm[(size_t)r*C + c];
    if (rend > rbeg) atomicAdd(&msum[g*C + c], sum);
}

__global__ void k_mlp1(const float* __restrict__ msum, const int* __restrict__ gstart,
                       const float* __restrict__ mW1, const float* __restrict__ mb1,
                       __half* __restrict__ r1h){
    int g = blockIdx.x, c = threadIdx.x;   // 128 threads
    int cnt = gstart[g+1] - gstart[g];
    float inv = 1.f / (float)(cnt > 1 ? cnt : 1);
    float acc = mb1[c];
    for (int k=0;k<128;k++) acc = fmaf(msum[g*128+k]*inv, mW1[k*128+c], acc);
    r1h[g*128+c] = __float2half(fmaxf(acc, 0.f));
}

__global__ void k_mlp2(const float* __restrict__ msum2, const int* __restrict__ gstart,
                       const float* __restrict__ mW2, const float* __restrict__ mb2,
                       float* __restrict__ r2){
    int g = blockIdx.x, c = threadIdx.x;
    if (c >= 32) return;
    int cnt = gstart[g+1] - gstart[g];
    float inv = 1.f / (float)(cnt > 1 ? cnt : 1);
    float acc = mb2[c];
    for (int k=0;k<32;k++) acc = fmaf(msum2[g*32+k]*inv, mW2[k*32+c], acc);
    r2[g*32+c] = fmaxf(acc, 0.f);
}

// ---------------- GEMM2 (MFMA fp16): y2 = ((h + r1h[batch]) @ W2) * dinv ----------------
__global__ __launch_bounds__(256) void k_gemm2(const __half* __restrict__ h, const __half* __restrict__ r1h,
                                               const int* __restrict__ batch, const __half* __restrict__ w2t,
                                               const float* __restrict__ dinv, __half* __restrict__ y2, int N){
    __shared__ __half Wl[32*136];
    int t = threadIdx.x;
    if (blockIdx.x==0 && t < 8)
        reinterpret_cast<uint2*>(y2 + (size_t)N*32)[t] = make_uint2(0u,0u);
    {
        const uint4* g = (const uint4*)w2t;
        uint4* l = (uint4*)Wl;
        for (int i = t; i < 544; i += 256) l[i] = g[i];
    }
    __syncthreads();
    int wv = t>>6, lane = t&63;
    int r0 = blockIdx.x*64 + wv*16;
    if (r0 >= N) return;
    int lr = lane & 15, lg = lane >> 4;
    int r = r0 + lr;
    bool rok = r < N;
    int rr = rok ? r : 0;
    const __half* hrow = h + (size_t)rr*128;
    const __half* vrow = r1h + (size_t)batch[rr]*128;
    floatx4 acc0 = (floatx4){0.f,0.f,0.f,0.f};
    floatx4 acc1 = (floatx4){0.f,0.f,0.f,0.f};
    #pragma unroll
    for (int ks=0; ks<4; ks++){
        int k0 = ks*32 + lg*8;
        uint4 hu = *reinterpret_cast<const uint4*>(hrow + k0);
        uint4 vu = *reinterpret_cast<const uint4*>(vrow + k0);
        __half2 b0 = __hadd2(*(__half2*)&hu.x, *(__half2*)&vu.x);
        __half2 b1_ = __hadd2(*(__half2*)&hu.y, *(__half2*)&vu.y);
        __half2 b2_ = __hadd2(*(__half2*)&hu.z, *(__half2*)&vu.z);
        __half2 b3_ = __hadd2(*(__half2*)&hu.w, *(__half2*)&vu.w);
        uint4 bu; bu.x=*(unsigned*)&b0; bu.y=*(unsigned*)&b1_; bu.z=*(unsigned*)&b2_; bu.w=*(unsigned*)&b3_;
        half8 bfrag = *reinterpret_cast<half8*>(&bu);
        half8 a0 = *reinterpret_cast<const half8*>(&Wl[(0*16 + lr)*136 + k0]);
        half8 a1 = *reinterpret_cast<const half8*>(&Wl[(1*16 + lr)*136 + k0]);
        acc0 = __builtin_amdgcn_mfma_f32_16x16x32_f16(a0, bfrag, acc0, 0, 0, 0);
        acc1 = __builtin_amdgcn_mfma_f32_16x16x32_f16(a1, bfrag, acc1, 0, 0, 0);
    }
    if (rok){
        float dv = dinv[r];
        {
            __half2 p0 = __floats2half2_rn(acc0[0]*dv, acc0[1]*dv);
            __half2 p1 = __floats2half2_rn(acc0[2]*dv, acc0[3]*dv);
            uint2 stv; stv.x = *(unsigned*)&p0; stv.y = *(unsigned*)&p1;
            *reinterpret_cast<uint2*>(&y2[(size_t)r*32 + 0 + lg*4]) = stv;
        }
        {
            __half2 p0 = __floats2half2_rn(acc1[0]*dv, acc1[1]*dv);
            __half2 p1 = __floats2half2_rn(acc1[2]*dv, acc1[3]*dv);
            uint2 stv; stv.x = *(unsigned*)&p0; stv.y = *(unsigned*)&p1;
            *reinterpret_cast<uint2*>(&y2[(size_t)r*32 + 16 + lg*4]) = stv;
        }
    }
}

// ---------------- layer-2 aggregation: octet-wave 8B gathers, zero-row, fp16 accum ----------------
__global__ void k_agg2h(const __half* __restrict__ y2, const float* __restrict__ dinv,
                        const float* __restrict__ b2, const int2* __restrict__ rs2,
                        const unsigned short* __restrict__ csr, float* __restrict__ Z, int N){
    int wid = (int)((blockIdx.x*blockDim.x + threadIdx.x) >> 6);
    if (wid >= N) return;
    int lane = threadIdx.x & 63;
    int o8 = lane >> 3, ol = lane & 7;
    int2 se = rs2[wid];
    int beg = se.x, end = se.y, len = end-beg;
    int olen = (len + 7) >> 3;
    int obeg = beg + o8*olen;
    int oend = obeg + olen; if (oend > end) oend = end;
    int mylen = oend - obeg; if (mylen < 0) mylen = 0;
    const char* yb = (const char*)y2;
    unsigned lofs = (unsigned)ol * 8u;
    float f0=0.f, f1=0.f, f2=0.f, f3=0.f;
    int iters = (olen + 7) >> 3;
    for (int c=0;c<iters;c++){
        int o = c*8 + ol;
        int idx = (o < mylen) ? (int)csr[obeg + o] : N;
        int tb = o8<<3;
        int s0 = __shfl(idx, tb+0);
        int s1 = __shfl(idx, tb+1);
        int s2 = __shfl(idx, tb+2);
        int s3 = __shfl(idx, tb+3);
        int s4 = __shfl(idx, tb+4);
        int s5 = __shfl(idx, tb+5);
        int s6 = __shfl(idx, tb+6);
        int s7 = __shfl(idx, tb+7);
        uint2 u0 = *(const uint2*)(yb + (((unsigned)s0<<6) + lofs));
        uint2 u1 = *(const uint2*)(yb + (((unsigned)s1<<6) + lofs));
        uint2 u2 = *(const uint2*)(yb + (((unsigned)s2<<6) + lofs));
        uint2 u3 = *(const uint2*)(yb + (((unsigned)s3<<6) + lofs));
        uint2 u4 = *(const uint2*)(yb + (((unsigned)s4<<6) + lofs));
        uint2 u5 = *(const uint2*)(yb + (((unsigned)s5<<6) + lofs));
        uint2 u6 = *(const uint2*)(yb + (((unsigned)s6<<6) + lofs));
        uint2 u7 = *(const uint2*)(yb + (((unsigned)s7<<6) + lofs));
        __half2 a0 = __float2half2_rn(0.f), a1 = a0;
        a0 = __hadd2(a0, *(__half2*)&u0.x); a1 = __hadd2(a1, *(__half2*)&u0.y);
        a0 = __hadd2(a0, *(__half2*)&u1.x); a1 = __hadd2(a1, *(__half2*)&u1.y);
        a0 = __hadd2(a0, *(__half2*)&u2.x); a1 = __hadd2(a1, *(__half2*)&u2.y);
        a0 = __hadd2(a0, *(__half2*)&u3.x); a1 = __hadd2(a1, *(__half2*)&u3.y);
        a0 = __hadd2(a0, *(__half2*)&u4.x); a1 = __hadd2(a1, *(__half2*)&u4.y);
        a0 = __hadd2(a0, *(__half2*)&u5.x); a1 = __hadd2(a1, *(__half2*)&u5.y);
        a0 = __hadd2(a0, *(__half2*)&u6.x); a1 = __hadd2(a1, *(__half2*)&u6.y);
        a0 = __hadd2(a0, *(__half2*)&u7.x); a1 = __hadd2(a1, *(__half2*)&u7.y);
        float2 t0 = __half22float2(a0); f0 += t0.x; f1 += t0.y;
        float2 t1 = __half22float2(a1); f2 += t1.x; f3 += t1.y;
    }
    f0 += __shfl_xor(f0,8);  f1 += __shfl_xor(f1,8);  f2 += __shfl_xor(f2,8);  f3 += __shfl_xor(f3,8);
    f0 += __shfl_xor(f0,16); f1 += __shfl_xor(f1,16); f2 += __shfl_xor(f2,16); f3 += __shfl_xor(f3,16);
    f0 += __shfl_xor(f0,32); f1 += __shfl_xor(f1,32); f2 += __shfl_xor(f2,32); f3 += __shfl_xor(f3,32);
    if (o8 == 0){
        uint2 su = *(const uint2*)(yb + (((unsigned)wid<<6) + lofs));   // self loop
        float2 s0 = __half22float2(*(__half2*)&su.x); f0 += s0.x; f1 += s0.y;
        float2 s1 = __half22float2(*(__half2*)&su.y); f2 += s1.x; f3 += s1.y;
        float dv = dinv[wid];
        float4 bb = ld4(&b2[ol*4]);
        float4 outv;
        outv.x = dv*f0 + bb.x; outv.y = dv*f1 + bb.y;
        outv.z = dv*f2 + bb.z; outv.w = dv*f3 + bb.w;
        *reinterpret_cast<float4*>(&Z[(size_t)wid*32 + ol*4]) = outv;
    }
}

// ---------------- + virtual node + softmax (in-place on d_out) ----------------
__global__ void k_softmax(float* __restrict__ Z, const float* __restrict__ r2,
                          const int* __restrict__ batch, int N){
    int r = blockIdx.x*8 + (threadIdx.x>>5);
    int c = threadIdx.x & 31;
    if (r >= N) return;
    float z = Z[(size_t)r*32+c] + r2[batch[r]*32 + c];
    float m = z;
    #pragma unroll
    for (int off=16; off>=1; off>>=1) m = fmaxf(m, __shfl_xor(m, off));
    float e = expf(z - m);
    float s = e;
    #pragma unroll
    for (int off=16; off>=1; off>>=1) s += __shfl_xor(s, off);
    Z[(size_t)r*32+c] = e / s;
}

extern "C" void kernel_launch(void* const* d_in, const int* in_sizes, int n_in,
                              void* d_out, int out_size, void* d_ws, size_t ws_size,
                              hipStream_t stream){
    const float* X   = (const float*)d_in[0];
    const float* W1  = (const float*)d_in[1];
    const float* b1  = (const float*)d_in[2];
    const float* W2  = (const float*)d_in[3];
    const float* b2  = (const float*)d_in[4];
    const float* mW1 = (const float*)d_in[5];
    const float* mb1 = (const float*)d_in[6];
    const float* mW2 = (const float*)d_in[7];
    const float* mb2 = (const float*)d_in[8];
    const int*   ei  = (const int*)d_in[9];
    const int*   batch = (const int*)d_in[10];
    int N = in_sizes[0] / 128;
    int E = in_sizes[9] / 2;
    const int* src = ei;
    const int* dst = ei + E;
    float* Zout = (float*)d_out;

    char* wsp = (char*)d_ws;
    size_t off = 0;
    auto alloc = [&](size_t bytes)->char*{
        char* p = wsp + off; off += (bytes + 255) & ~(size_t)255; return p;
    };
    // zero zone
    int*   bfill = (int*)  alloc((size_t)MAXNB*4);
    float* msum  = (float*)alloc((size_t)GNUM*128*4);
    float* msum2 = (float*)alloc((size_t)GNUM*32*4);
    size_t zero_bytes = off;
    // rest
    int NB = (N + 127) >> 7;            // 391
    int2*  rs2   = (int2*) alloc((size_t)N*8);
    int*   gstart= (int*)  alloc((GNUM+1)*4);
    unsigned* ebuf = (unsigned*)alloc((size_t)NB*CAP*4);
    unsigned short* csr = (unsigned short*)alloc((size_t)NB*CAP*2);
    float* dinvp = (float*)alloc((size_t)N*4);
    __half* w1t  = (__half*)alloc((size_t)W1T_ELEMS*2);
    __half* w2t  = (__half*)alloc((size_t)W2T_ELEMS*2);
    __half* yh   = (__half*)alloc((size_t)(N+1)*128*2);   // +1: zero row
    __half* h    = (__half*)alloc((size_t)N*128*2);
    __half* y2h  = (__half*)alloc((size_t)(N+1)*32*2);    // +1: zero row
    __half* r1buf= (__half*)alloc((size_t)GNUM*128*2);
    float* r2buf = (float*)alloc((size_t)GNUM*32*4);
    (void)ws_size; (void)n_in; (void)out_size;

    hipMemsetAsync(d_ws, 0, zero_bytes, stream);

    int EB = (E + CHUNK-1) / CHUNK;     // 391
    int PREP = (W1T_ELEMS + W2T_ELEMS + 255)/256;   // 85

    k_scatter      <<<EB + PREP, 256, 0, stream>>>(src, dst, E, NB, bfill, ebuf, W1, W2, w1t, w2t, EB);
    k_bucket_finish<<<NB, 256, 0, stream>>>(ebuf, bfill, rs2, csr, dinvp, batch, gstart, N);

    k_gemm1 <<<(N+63)/64, 256, 0, stream>>>(X, w1t, dinvp, yh, N);
    k_agg1  <<<(N+3)/4, 256, 0, stream>>>(yh, dinvp, b1, rs2, csr, h, N);

    k_mpoolh<<<dim3(GNUM,8), 64, 0, stream>>>(h, gstart, msum);
    k_mlp1  <<<GNUM, 128, 0, stream>>>(msum, gstart, mW1, mb1, r1buf);

    k_gemm2 <<<(N+63)/64, 256, 0, stream>>>(h, r1buf, batch, w2t, dinvp, y2h, N);
    k_agg2h <<<(N+3)/4, 256, 0, stream>>>(y2h, dinvp, b2, rs2, csr, Zout, N);

    k_mpool <<<dim3(GNUM,8), 64, 0, stream>>>(Zout, gstart, msum2, 32);
    k_mlp2  <<<GNUM, 64, 0, stream>>>(msum2, gstart, mW2, mb2, r2buf);
    k_softmax<<<(N+7)/8, 256, 0, stream>>>(Zout, r2buf, batch, N);
}